// Round 3
// baseline (4396.585 us; speedup 1.0000x reference)
//
#include <hip/hip_runtime.h>
#include <stdint.h>

typedef unsigned short u16;
typedef __attribute__((ext_vector_type(8))) short short8;     // 8 bf16 (MFMA A/B frag)
typedef __attribute__((ext_vector_type(4))) float float4_;    // MFMA C/D frag
typedef __attribute__((ext_vector_type(4))) unsigned short us4;

#define NB 8
#define LL 4096
#define DD 1024
#define CC 64
#define NCH 64   // LL/CC

__device__ __forceinline__ u16 f2bf(float f) {
  union { float f; uint32_t u; } v; v.f = f;
  uint32_t u = v.u;
  return (u16)((u + 0x7fffu + ((u >> 16) & 1u)) >> 16);   // RNE
}
__device__ __forceinline__ float bf2f(u16 h) {
  union { uint32_t u; float f; } v; v.u = ((uint32_t)h) << 16;
  return v.f;
}
__device__ __forceinline__ float4_ mfma16(short8 a, short8 b, float4_ c) {
  return __builtin_amdgcn_mfma_f32_16x16x32_bf16(a, b, c, 0, 0, 0);
}
// packed f32x2 -> bf16x2, RNE (same rounding as f2bf)
__device__ __forceinline__ uint32_t cvtpk(float lo, float hi) {
  uint32_t r;
  asm("v_cvt_pk_bf16_f32 %0, %1, %2" : "=v"(r) : "v"(lo), "v"(hi));
  return r;
}
union S8U { short8 s; uint32_t w[4]; };

// ---------------- dtype detect: flag=1 if inputs are bf16, 0 if f32 ----------------
__global__ void k_detect(const uint32_t* __restrict__ X, int* __restrict__ flag) {
  if (threadIdx.x == 0 && blockIdx.x == 0) {
    int votes = 0;
    for (int i = 0; i < 64; ++i) {
      uint32_t w = X[i];
      uint32_t e = (w >> 7) & 0xFF;   // exponent field of the LOW u16 viewed as bf16
      votes += (e > 134 || e < 110) ? 1 : 0;
    }
    *flag = (votes < 8) ? 1 : 0;
  }
}

// ---------------- convert input tensor -> bf16 (dual dtype) ----------------
__global__ __launch_bounds__(256) void k_convert(const void* __restrict__ src, u16* __restrict__ dst,
                                                 long n8, const int* __restrict__ flag) {
  long i = (long)blockIdx.x * 256 + threadIdx.x;   // index of 8-element chunk
  if (i >= n8) return;
  if (*flag) {
    ((short8*)dst)[i] = ((const short8*)src)[i];
  } else {
    const float4_* s = (const float4_*)src;
    float4_ a = s[2 * i], b = s[2 * i + 1];
    short8 o;
#pragma unroll
    for (int j = 0; j < 4; ++j) { o[j] = (short)f2bf(a[j]); o[4 + j] = (short)f2bf(b[j]); }
    ((short8*)dst)[i] = o;
  }
}

// ---------------- big NT GEMM: Out(M x 1024) = A(M x 1024) @ W(1024 x 1024)^T + bias ----------------
template <bool DUAL>
__device__ __forceinline__ void gemm128(const u16* __restrict__ A, const u16* __restrict__ W,
                                        const u16* __restrict__ bias, void* __restrict__ Out,
                                        int m0, int n0, const int* __restrict__ flag) {
  __shared__ __attribute__((aligned(16))) u16 As[128 * 64];
  __shared__ __attribute__((aligned(16))) u16 Bs[128 * 64];
  const int tid = threadIdx.x, lane = tid & 63, wv = tid >> 6;
  float4_ acc[2][8];
#pragma unroll
  for (int i = 0; i < 2; ++i)
#pragma unroll
    for (int j = 0; j < 8; ++j) acc[i][j] = (float4_)0.f;

  for (int kk = 0; kk < DD; kk += 64) {
#pragma unroll
    for (int i = 0; i < 4; ++i) {
      int e = tid + 256 * i;
      int row = e >> 3, col = (e & 7) * 8;
      *(short8*)&As[row * 64 + col] = *(const short8*)(A + (size_t)(m0 + row) * DD + kk + col);
      *(short8*)&Bs[row * 64 + col] = *(const short8*)(W + (size_t)(n0 + row) * DD + kk + col);
    }
    __syncthreads();
#pragma unroll
    for (int ks = 0; ks < 2; ++ks) {
      short8 af[2];
#pragma unroll
      for (int mt = 0; mt < 2; ++mt)
        af[mt] = *(const short8*)&As[(32 * wv + 16 * mt + (lane & 15)) * 64 + ks * 32 + (lane >> 4) * 8];
#pragma unroll
      for (int nt = 0; nt < 8; ++nt) {
        short8 bf = *(const short8*)&Bs[(16 * nt + (lane & 15)) * 64 + ks * 32 + (lane >> 4) * 8];
#pragma unroll
        for (int mt = 0; mt < 2; ++mt) acc[mt][nt] = mfma16(af[mt], bf, acc[mt][nt]);
      }
    }
    __syncthreads();
  }
  const bool obf = DUAL ? (*flag != 0) : true;
#pragma unroll
  for (int mt = 0; mt < 2; ++mt)
#pragma unroll
    for (int nt = 0; nt < 8; ++nt) {
      int rg = m0 + 32 * wv + 16 * mt + ((lane >> 4) << 2);
      int cg = n0 + 16 * nt + (lane & 15);
      float bv = bf2f(bias[cg]);
#pragma unroll
      for (int r = 0; r < 4; ++r) {
        float o = acc[mt][nt][r] + bv;
        if (obf) ((u16*)Out)[(size_t)(rg + r) * DD + cg] = f2bf(o);
        else     ((float*)Out)[(size_t)(rg + r) * DD + cg] = o;
      }
    }
}

__global__ __launch_bounds__(256) void k_gemm_qkv(const u16* __restrict__ X,
    const u16* __restrict__ Wq, const u16* __restrict__ bq,
    const u16* __restrict__ Wk, const u16* __restrict__ bk,
    const u16* __restrict__ Wv, const u16* __restrict__ bv,
    u16* __restrict__ Qo, u16* __restrict__ Ko, u16* __restrict__ Vo) {
  int nb = blockIdx.x;  // 0..23
  int mat = nb >> 3, nt = nb & 7;
  const u16 *W, *bi; u16* O;
  if (mat == 0)      { W = Wq; bi = bq; O = Qo; }
  else if (mat == 1) { W = Wk; bi = bk; O = Ko; }
  else               { W = Wv; bi = bv; O = Vo; }
  gemm128<false>(X, W, bi, O, blockIdx.y * 128, nt * 128, nullptr);
}

__global__ __launch_bounds__(256) void k_gemm_o(const u16* __restrict__ A,
    const u16* __restrict__ Wo, const u16* __restrict__ bo, void* __restrict__ Out,
    const int* __restrict__ flag) {
  gemm128<true>(A, Wo, bo, Out, blockIdx.y * 128, blockIdx.x * 128, flag);
}

// ---------------- prep: per (chunk, batch): beta, T2, U0 (over V), A=tril(QK^T),
//                  W = T2@K (ALL chunks) -> Wall, and K^T emission -> KTg (B,D,L) ----------------
__global__ __launch_bounds__(256) void k_prep(const u16* __restrict__ Q, const u16* __restrict__ K,
                                              u16* __restrict__ V /* V in, U0 out (in place) */,
                                              u16* __restrict__ Aout, u16* __restrict__ Wall,
                                              u16* __restrict__ KTg) {
  const int ch = blockIdx.x, b = blockIdx.y;
  const size_t row0 = (size_t)b * LL + (size_t)ch * CC;
  const int tid = threadIdx.x, lane = tid & 63, wv = tid >> 6;

  __shared__ __attribute__((aligned(16))) float Gs[64 * 65];   // reused as KTs (u16 64x72) in phase B
  __shared__ __attribute__((aligned(16))) float Ts[64 * 65];   // reused as VTs (u16 64x72) in phase B
  __shared__ __attribute__((aligned(16))) u16 Kt[64 * 64];
  __shared__ __attribute__((aligned(16))) u16 Qt[64 * 64];
  __shared__ __attribute__((aligned(16))) u16 T2s[64 * 72];
  __shared__ float betas[64];

  float4_ accG[4], accA[4];
#pragma unroll
  for (int ct = 0; ct < 4; ++ct) { accG[ct] = (float4_)0.f; accA[ct] = (float4_)0.f; }

  // phase A: G = K K^T, Araw = Q K^T  (K-streamed)
  for (int kk = 0; kk < DD; kk += 64) {
#pragma unroll
    for (int i = 0; i < 2; ++i) {
      int e = tid + 256 * i;
      int row = e >> 3, col = (e & 7) * 8;
      *(short8*)&Kt[row * 64 + col] = *(const short8*)(K + (row0 + row) * DD + kk + col);
      *(short8*)&Qt[row * 64 + col] = *(const short8*)(Q + (row0 + row) * DD + kk + col);
    }
    __syncthreads();
#pragma unroll
    for (int ks = 0; ks < 2; ++ks) {
      short8 ak = *(const short8*)&Kt[(16 * wv + (lane & 15)) * 64 + ks * 32 + (lane >> 4) * 8];
      short8 aq = *(const short8*)&Qt[(16 * wv + (lane & 15)) * 64 + ks * 32 + (lane >> 4) * 8];
#pragma unroll
      for (int ct = 0; ct < 4; ++ct) {
        short8 bk = *(const short8*)&Kt[(16 * ct + (lane & 15)) * 64 + ks * 32 + (lane >> 4) * 8];
        accG[ct] = mfma16(ak, bk, accG[ct]);
        accA[ct] = mfma16(aq, bk, accA[ct]);
      }
    }
    __syncthreads();
  }
  u16* Abase = Aout + (size_t)(b * NCH + ch) * (CC * CC);
#pragma unroll
  for (int ct = 0; ct < 4; ++ct) {
    int i0 = 16 * wv + ((lane >> 4) << 2);
    int c = 16 * ct + (lane & 15);
#pragma unroll
    for (int r = 0; r < 4; ++r) {
      int i = i0 + r;
      Gs[i * 65 + c] = accG[ct][r];
      Abase[i * 64 + c] = f2bf((c <= i) ? accA[ct][r] : 0.f);
    }
  }
  __syncthreads();
  if (tid < 64) betas[tid] = 1.f / (Gs[tid * 65 + tid] + 1e-6f);
  __syncthreads();
  for (int e = tid; e < 4096; e += 256) {
    int i = e >> 6, c = e & 63;
    Ts[i * 65 + c] = (c < i) ? (-betas[i] * Gs[i * 65 + c]) : 0.f;
  }
  __syncthreads();
  // forward substitution (reference exact recurrence)
  for (int i = 1; i < 64; ++i) {
    float rv = 0.f, acc = 0.f;
    if (tid < 64) {
      rv = Ts[i * 65 + tid];
      for (int j = 1; j < i; ++j) {
        float a = __shfl(rv, j);
        acc += a * Ts[j * 65 + tid];
      }
    }
    __syncthreads();
    if (tid < i) Ts[i * 65 + tid] = rv + acc;
    __syncthreads();
  }
  if (tid < 64) Ts[tid * 65 + tid] += 1.f;
  __syncthreads();
  for (int e = tid; e < 4096; e += 256) {   // T2[i][j] = T[i][j]*beta[j] (LDS only)
    int i = e >> 6, j = e & 63;
    T2s[i * 72 + j] = f2bf(Ts[i * 65 + j] * betas[j]);
  }
  __syncthreads();

  // phase B: U0 = T2 @ V (over V); W = T2 @ K -> Wall (all chunks); emit K^T -> KTg
  u16* KTs = (u16*)Gs;  // 64 x 72
  u16* VTs = (u16*)Ts;  // 64 x 72
  for (int kk = 0; kk < DD; kk += 64) {
#pragma unroll
    for (int rep = 0; rep < 2; ++rep) {   // transpose V and K tiles into LDS
      int t = tid >> 2;
      int c0 = (tid & 3) * 8 + rep * 32;
      short8 vv = *(const short8*)(V + (row0 + t) * DD + kk + c0);
      short8 vk = *(const short8*)(K + (row0 + t) * DD + kk + c0);
#pragma unroll
      for (int e = 0; e < 8; ++e) { VTs[(c0 + e) * 72 + t] = (u16)vv[e]; KTs[(c0 + e) * 72 + t] = (u16)vk[e]; }
    }
    __syncthreads();
    // emit K^T tile to global: KTg[(b, kk+jl, ch*64 + t)]
#pragma unroll
    for (int w2 = 0; w2 < 2; ++w2) {
      int e = tid + 256 * w2;
      int jl = e >> 3, toff = (e & 7) * 8;
      *(short8*)(KTg + ((size_t)b * DD + kk + jl) * LL + (size_t)ch * CC + toff) =
          *(const short8*)&KTs[jl * 72 + toff];
    }
    float4_ accU[4], accW[4];
#pragma unroll
    for (int ct = 0; ct < 4; ++ct) { accU[ct] = (float4_)0.f; accW[ct] = (float4_)0.f; }
#pragma unroll
    for (int ks = 0; ks < 2; ++ks) {
      short8 a2 = *(const short8*)&T2s[(16 * wv + (lane & 15)) * 72 + ks * 32 + (lane >> 4) * 8];
#pragma unroll
      for (int ct = 0; ct < 4; ++ct) {
        short8 bu = *(const short8*)&VTs[(16 * ct + (lane & 15)) * 72 + ks * 32 + (lane >> 4) * 8];
        short8 bw = *(const short8*)&KTs[(16 * ct + (lane & 15)) * 72 + ks * 32 + (lane >> 4) * 8];
        accU[ct] = mfma16(a2, bu, accU[ct]);
        accW[ct] = mfma16(a2, bw, accW[ct]);
      }
    }
#pragma unroll
    for (int ct = 0; ct < 4; ++ct) {
      int i0 = 16 * wv + ((lane >> 4) << 2);
      int c = kk + 16 * ct + (lane & 15);
#pragma unroll
      for (int r = 0; r < 4; ++r) {
        V[(row0 + i0 + r) * DD + c]    = f2bf(accU[ct][r]);   // U0 over V
        Wall[(row0 + i0 + r) * DD + c] = f2bf(accW[ct][r]);   // W for all chunks
      }
    }
    __syncthreads();
  }
}

// ---------------- fused scan: one persistent 512-thread WG per (b, 32-col slice of d_v) ---------
// S^T[32][1028] f32 in static LDS across all 64 chunks. 8 waves: j/dj split 128 per wave.
// per chunk: phase1 u-=W@S, oq+=Q@S (atomic f32 reduce) | barrier | ub frags from u_acc (cvt_pk)
// | barrier | phase3 S+=K^T@u, phase4 o=A@u+oq (owner wave zeroes oq), init next u_acc | barrier
__global__ __launch_bounds__(512, 2) void k_scan_fused(
    const u16* __restrict__ Q, const u16* __restrict__ Wg, const u16* __restrict__ KTg,
    const u16* __restrict__ U0, const u16* __restrict__ Ag, u16* __restrict__ Og) {
  __shared__ __attribute__((aligned(16))) float S[32 * 1028];     // 131584 B
  __shared__ __attribute__((aligned(16))) float u_acc[64 * 33];   //   8448 B
  __shared__ __attribute__((aligned(16))) float oq_acc[64 * 33];  //   8448 B -> 148480 total

  const int b = blockIdx.x & 7;               // XCD-affinity: batch b -> XCD b
  const int dc0 = (blockIdx.x >> 3) * 32;
  const int tid = threadIdx.x, lane = tid & 63, wv = tid >> 6;   // wv in 0..7
  const int r15 = lane & 15, hi = lane >> 4;  // hi in 0..3
  const int khi = hi * 8;
  const int tIq = tid >> 3, cIq = (tid & 7) * 4;

  for (int i = tid; i < 32 * 1028; i += 512) S[i] = 0.f;
  {  // init u_acc = U0(ch0), oq_acc = 0
    us4 v = *(const us4*)(U0 + ((size_t)b * LL + tIq) * DD + dc0 + cIq);
#pragma unroll
    for (int e = 0; e < 4; ++e) {
      u_acc[tIq * 33 + cIq + e] = bf2f(v[e]);
      oq_acc[tIq * 33 + cIq + e] = 0.f;
    }
  }
  __syncthreads();

  for (int ch = 0; ch < NCH; ++ch) {
    const size_t row0 = (size_t)b * LL + (size_t)ch * CC;
    // ---- phase 1: wave wv covers j in [128*wv, 128*wv+128)
    {
      float4_ up[4][2], qp[4][2];
#pragma unroll
      for (int tt = 0; tt < 4; ++tt)
#pragma unroll
        for (int dt = 0; dt < 2; ++dt) { up[tt][dt] = (float4_)0.f; qp[tt][dt] = (float4_)0.f; }
#pragma unroll
      for (int ks = 0; ks < 4; ++ks) {
        const int j0 = wv * 128 + ks * 32 + khi;
        short8 sf[2];
#pragma unroll
        for (int dt = 0; dt < 2; ++dt) {
          const float* sp = &S[(dt * 16 + r15) * 1028 + j0];
          float4_ x0 = *(const float4_*)sp;
          float4_ x1 = *(const float4_*)(sp + 4);
          S8U u;
          u.w[0] = cvtpk(x0[0], x0[1]);
          u.w[1] = cvtpk(x0[2], x0[3]);
          u.w[2] = cvtpk(x1[0], x1[1]);
          u.w[3] = cvtpk(x1[2], x1[3]);
          sf[dt] = u.s;
        }
#pragma unroll
        for (int tt = 0; tt < 4; ++tt) {
          const size_t rbase = (row0 + tt * 16 + r15) * DD + j0;
          short8 wf = *(const short8*)(Wg + rbase);
          short8 qf = *(const short8*)(Q + rbase);
#pragma unroll
          for (int dt = 0; dt < 2; ++dt) {
            up[tt][dt] = mfma16(wf, sf[dt], up[tt][dt]);
            qp[tt][dt] = mfma16(qf, sf[dt], qp[tt][dt]);
          }
        }
      }
#pragma unroll
      for (int tt = 0; tt < 4; ++tt)
#pragma unroll
        for (int dt = 0; dt < 2; ++dt) {
          const int t0 = tt * 16 + hi * 4, dc = dt * 16 + r15;
#pragma unroll
          for (int r = 0; r < 4; ++r) {
            atomicAdd(&u_acc[(t0 + r) * 33 + dc], -up[tt][dt][r]);
            atomicAdd(&oq_acc[(t0 + r) * 33 + dc], qp[tt][dt][r]);
          }
        }
    }
    __syncthreads();   // barrier A: u/oq reductions complete
    // ---- build ub frags straight from f32 u_acc (no uT staging)
    short8 ub[2][2];
#pragma unroll
    for (int dt = 0; dt < 2; ++dt) {
      const int dc = dt * 16 + r15;
#pragma unroll
      for (int ks = 0; ks < 2; ++ks) {
        S8U u;
#pragma unroll
        for (int w2 = 0; w2 < 4; ++w2) {
          float lo = u_acc[(ks * 32 + khi + 2 * w2) * 33 + dc];
          float hi2 = u_acc[(ks * 32 + khi + 2 * w2 + 1) * 33 + dc];
          u.w[w2] = cvtpk(lo, hi2);
        }
        ub[dt][ks] = u.s;
      }
    }
    __syncthreads();   // barrier B: ub reads done before u_acc re-init below
    // ---- phase 3: S[dc][dj] += sum_t u[t,dc] K[t,dj], wave wv's 128-wide dj slice
    {
      const size_t ktb = ((size_t)b * DD) * LL + (size_t)ch * CC;
#pragma unroll 4
      for (int djt = 0; djt < 8; ++djt) {
        const int dj0 = wv * 128 + djt * 16;
        short8 kf0 = *(const short8*)(KTg + ktb + (size_t)(dj0 + r15) * LL + khi);
        short8 kf1 = *(const short8*)(KTg + ktb + (size_t)(dj0 + r15) * LL + 32 + khi);
#pragma unroll
        for (int dt = 0; dt < 2; ++dt) {
          float* sp = &S[(dt * 16 + r15) * 1028 + dj0 + hi * 4];
          float4_ c = *(const float4_*)sp;
          c = mfma16(kf0, ub[dt][0], c);
          c = mfma16(kf1, ub[dt][1], c);
          *(float4_*)sp = c;
        }
      }
      // ---- phase 4: o = A@u + oq -> Og; wave owns (tt = wv&3, dtw = wv>>2) tile; zero oq after
      const int tt = wv & 3, dtw = wv >> 2;
      const u16* Ab = Ag + (size_t)(b * NCH + ch) * (CC * CC);
      short8 af0 = *(const short8*)(Ab + (tt * 16 + r15) * CC + khi);
      short8 af1 = *(const short8*)(Ab + (tt * 16 + r15) * CC + 32 + khi);
      const int t0 = tt * 16 + hi * 4;
      const int dc = dtw * 16 + r15;
      float4_ c;
#pragma unroll
      for (int r = 0; r < 4; ++r) { c[r] = oq_acc[(t0 + r) * 33 + dc]; oq_acc[(t0 + r) * 33 + dc] = 0.f; }
      c = mfma16(af0, ub[dtw][0], c);
      c = mfma16(af1, ub[dtw][1], c);
#pragma unroll
      for (int r = 0; r < 4; ++r)
        Og[(row0 + t0 + r) * DD + dc0 + dc] = f2bf(c[r]);
      // ---- init u_acc for next chunk (u_acc free after barrier B)
      if (ch + 1 < NCH) {
        us4 v = *(const us4*)(U0 + (row0 + CC + tIq) * DD + dc0 + cIq);
#pragma unroll
        for (int e = 0; e < 4; ++e) u_acc[tIq * 33 + cIq + e] = bf2f(v[e]);
      }
    }
    __syncthreads();   // barrier C: S/oq/u_acc consistent for next chunk
  }
}

extern "C" void kernel_launch(void* const* d_in, const int* in_sizes, int n_in,
                              void* d_out, int out_size, void* d_ws, size_t ws_size,
                              hipStream_t stream) {
  (void)in_sizes; (void)n_in; (void)out_size; (void)ws_size;
  const void* X  = d_in[0];
  // d_in[1] = chunk (=64), hard-coded
  const void* Wq = d_in[2]; const void* bq = d_in[3];
  const void* Wk = d_in[4]; const void* bk = d_in[5];
  const void* Wv = d_in[6]; const void* bv = d_in[7];
  const void* Wo = d_in[8]; const void* bo = d_in[9];

  char* ws = (char*)d_ws;
  int* flag = (int*)ws;
  char* p = ws + 256;
  const size_t E2 = (size_t)NB * LL * DD * 2;                  // 64 MiB per bf16 (B,L,D)
  u16* xb   = (u16*)p; p += E2;                                // X bf16; K^T (B,D,L) overlays after QKV
  u16* kt   = xb;
  u16* wqb  = (u16*)p; p += (size_t)DD * DD * 2;
  u16* wkb  = (u16*)p; p += (size_t)DD * DD * 2;
  u16* wvb  = (u16*)p; p += (size_t)DD * DD * 2;
  u16* wob  = (u16*)p; p += (size_t)DD * DD * 2;
  u16* bqb  = (u16*)p; p += 4096;
  u16* bkb  = (u16*)p; p += 4096;
  u16* bvb  = (u16*)p; p += 4096;
  u16* bob  = (u16*)p; p += 4096;
  u16* q_ws = (u16*)p; p += E2;                                // Q
  u16* k_ws = (u16*)p; p += E2;                                // K; scan writes o (Opre) here
  u16* v_ws = (u16*)p; p += E2;                                // V -> U0 in place
  u16* a_ws = (u16*)p; p += (size_t)NB * NCH * CC * CC * 2;    // 4 MiB
  u16* w_all = (u16*)p; p += E2;                               // W = T2@K for all chunks
  // total ~268 MiB

  k_detect<<<1, 64, 0, stream>>>((const uint32_t*)X, flag);
  const long nX = (long)NB * LL * DD / 8;
  k_convert<<<(nX + 255) / 256, 256, 0, stream>>>(X, xb, nX, flag);
  const long nW = (long)DD * DD / 8;
  k_convert<<<(nW + 255) / 256, 256, 0, stream>>>(Wq, wqb, nW, flag);
  k_convert<<<(nW + 255) / 256, 256, 0, stream>>>(Wk, wkb, nW, flag);
  k_convert<<<(nW + 255) / 256, 256, 0, stream>>>(Wv, wvb, nW, flag);
  k_convert<<<(nW + 255) / 256, 256, 0, stream>>>(Wo, wob, nW, flag);
  const long nBias = DD / 8;
  k_convert<<<1, 256, 0, stream>>>(bq, bqb, nBias, flag);
  k_convert<<<1, 256, 0, stream>>>(bk, bkb, nBias, flag);
  k_convert<<<1, 256, 0, stream>>>(bv, bvb, nBias, flag);
  k_convert<<<1, 256, 0, stream>>>(bo, bob, nBias, flag);

  k_gemm_qkv<<<dim3(24, 256), 256, 0, stream>>>(xb, wqb, bqb, wkb, bkb, wvb, bvb, q_ws, k_ws, v_ws);
  k_prep<<<dim3(64, 8), 256, 0, stream>>>(q_ws, k_ws, v_ws, a_ws, w_all, kt);
  k_scan_fused<<<dim3(256), 512, 0, stream>>>(q_ws, w_all, kt, v_ws, a_ws, k_ws);
  k_gemm_o<<<dim3(8, 256), 256, 0, stream>>>(k_ws, wob, bob, d_out, flag);
}

// Round 4
// 3321.627 us; speedup vs baseline: 1.3236x; 1.3236x over previous
//
#include <hip/hip_runtime.h>
#include <stdint.h>

typedef unsigned short u16;
typedef __attribute__((ext_vector_type(8))) short short8;     // 8 bf16 (MFMA A/B frag)
typedef __attribute__((ext_vector_type(4))) float float4_;    // MFMA C/D frag
typedef __attribute__((ext_vector_type(4))) unsigned short us4;

#define NB 8
#define LL 4096
#define DD 1024
#define CC 64
#define NCH 64   // LL/CC

__device__ __forceinline__ u16 f2bf(float f) {
  union { float f; uint32_t u; } v; v.f = f;
  uint32_t u = v.u;
  return (u16)((u + 0x7fffu + ((u >> 16) & 1u)) >> 16);   // RNE
}
__device__ __forceinline__ float bf2f(u16 h) {
  union { uint32_t u; float f; } v; v.u = ((uint32_t)h) << 16;
  return v.f;
}
__device__ __forceinline__ float4_ mfma16(short8 a, short8 b, float4_ c) {
  return __builtin_amdgcn_mfma_f32_16x16x32_bf16(a, b, c, 0, 0, 0);
}
// packed f32x2 -> bf16x2, RNE (same rounding as f2bf)
__device__ __forceinline__ uint32_t cvtpk(float lo, float hi) {
  uint32_t r;
  asm("v_cvt_pk_bf16_f32 %0, %1, %2" : "=v"(r) : "v"(lo), "v"(hi));
  return r;
}
union S8U { short8 s; uint32_t w[4]; };

// ---------------- dtype detect: flag=1 if inputs are bf16, 0 if f32 ----------------
__global__ void k_detect(const uint32_t* __restrict__ X, int* __restrict__ flag) {
  if (threadIdx.x == 0 && blockIdx.x == 0) {
    int votes = 0;
    for (int i = 0; i < 64; ++i) {
      uint32_t w = X[i];
      uint32_t e = (w >> 7) & 0xFF;   // exponent field of the LOW u16 viewed as bf16
      votes += (e > 134 || e < 110) ? 1 : 0;
    }
    *flag = (votes < 8) ? 1 : 0;
  }
}

// ---------------- convert input tensor -> bf16 (dual dtype) ----------------
__global__ __launch_bounds__(256) void k_convert(const void* __restrict__ src, u16* __restrict__ dst,
                                                 long n8, const int* __restrict__ flag) {
  long i = (long)blockIdx.x * 256 + threadIdx.x;   // index of 8-element chunk
  if (i >= n8) return;
  if (*flag) {
    ((short8*)dst)[i] = ((const short8*)src)[i];
  } else {
    const float4_* s = (const float4_*)src;
    float4_ a = s[2 * i], b = s[2 * i + 1];
    short8 o;
#pragma unroll
    for (int j = 0; j < 4; ++j) { o[j] = (short)f2bf(a[j]); o[4 + j] = (short)f2bf(b[j]); }
    ((short8*)dst)[i] = o;
  }
}

// ---------------- big NT GEMM: Out(M x 1024) = A(M x 1024) @ W(1024 x 1024)^T + bias ----------------
template <bool DUAL>
__device__ __forceinline__ void gemm128(const u16* __restrict__ A, const u16* __restrict__ W,
                                        const u16* __restrict__ bias, void* __restrict__ Out,
                                        int m0, int n0, const int* __restrict__ flag) {
  __shared__ __attribute__((aligned(16))) u16 As[128 * 64];
  __shared__ __attribute__((aligned(16))) u16 Bs[128 * 64];
  const int tid = threadIdx.x, lane = tid & 63, wv = tid >> 6;
  float4_ acc[2][8];
#pragma unroll
  for (int i = 0; i < 2; ++i)
#pragma unroll
    for (int j = 0; j < 8; ++j) acc[i][j] = (float4_)0.f;

  for (int kk = 0; kk < DD; kk += 64) {
#pragma unroll
    for (int i = 0; i < 4; ++i) {
      int e = tid + 256 * i;
      int row = e >> 3, col = (e & 7) * 8;
      *(short8*)&As[row * 64 + col] = *(const short8*)(A + (size_t)(m0 + row) * DD + kk + col);
      *(short8*)&Bs[row * 64 + col] = *(const short8*)(W + (size_t)(n0 + row) * DD + kk + col);
    }
    __syncthreads();
#pragma unroll
    for (int ks = 0; ks < 2; ++ks) {
      short8 af[2];
#pragma unroll
      for (int mt = 0; mt < 2; ++mt)
        af[mt] = *(const short8*)&As[(32 * wv + 16 * mt + (lane & 15)) * 64 + ks * 32 + (lane >> 4) * 8];
#pragma unroll
      for (int nt = 0; nt < 8; ++nt) {
        short8 bf = *(const short8*)&Bs[(16 * nt + (lane & 15)) * 64 + ks * 32 + (lane >> 4) * 8];
#pragma unroll
        for (int mt = 0; mt < 2; ++mt) acc[mt][nt] = mfma16(af[mt], bf, acc[mt][nt]);
      }
    }
    __syncthreads();
  }
  const bool obf = DUAL ? (*flag != 0) : true;
#pragma unroll
  for (int mt = 0; mt < 2; ++mt)
#pragma unroll
    for (int nt = 0; nt < 8; ++nt) {
      int rg = m0 + 32 * wv + 16 * mt + ((lane >> 4) << 2);
      int cg = n0 + 16 * nt + (lane & 15);
      float bv = bf2f(bias[cg]);
#pragma unroll
      for (int r = 0; r < 4; ++r) {
        float o = acc[mt][nt][r] + bv;
        if (obf) ((u16*)Out)[(size_t)(rg + r) * DD + cg] = f2bf(o);
        else     ((float*)Out)[(size_t)(rg + r) * DD + cg] = o;
      }
    }
}

__global__ __launch_bounds__(256) void k_gemm_qkv(const u16* __restrict__ X,
    const u16* __restrict__ Wq, const u16* __restrict__ bq,
    const u16* __restrict__ Wk, const u16* __restrict__ bk,
    const u16* __restrict__ Wv, const u16* __restrict__ bv,
    u16* __restrict__ Qo, u16* __restrict__ Ko, u16* __restrict__ Vo) {
  int nb = blockIdx.x;  // 0..23
  int mat = nb >> 3, nt = nb & 7;
  const u16 *W, *bi; u16* O;
  if (mat == 0)      { W = Wq; bi = bq; O = Qo; }
  else if (mat == 1) { W = Wk; bi = bk; O = Ko; }
  else               { W = Wv; bi = bv; O = Vo; }
  gemm128<false>(X, W, bi, O, blockIdx.y * 128, nt * 128, nullptr);
}

__global__ __launch_bounds__(256) void k_gemm_o(const u16* __restrict__ A,
    const u16* __restrict__ Wo, const u16* __restrict__ bo, void* __restrict__ Out,
    const int* __restrict__ flag) {
  gemm128<true>(A, Wo, bo, Out, blockIdx.y * 128, blockIdx.x * 128, flag);
}

// ---------------- prep: per (chunk, batch): beta, T2, U0 (over V), A=tril(QK^T),
//                  W = T2@K (ALL chunks) -> Wall, and K^T emission -> KTg (B,D,L) ----------------
__global__ __launch_bounds__(256) void k_prep(const u16* __restrict__ Q, const u16* __restrict__ K,
                                              u16* __restrict__ V /* V in, U0 out (in place) */,
                                              u16* __restrict__ Aout, u16* __restrict__ Wall,
                                              u16* __restrict__ KTg) {
  const int ch = blockIdx.x, b = blockIdx.y;
  const size_t row0 = (size_t)b * LL + (size_t)ch * CC;
  const int tid = threadIdx.x, lane = tid & 63, wv = tid >> 6;

  __shared__ __attribute__((aligned(16))) float Gs[64 * 65];   // reused as KTs (u16 64x72) in phase B
  __shared__ __attribute__((aligned(16))) float Ts[64 * 65];   // reused as VTs (u16 64x72) in phase B
  __shared__ __attribute__((aligned(16))) u16 Kt[64 * 64];
  __shared__ __attribute__((aligned(16))) u16 Qt[64 * 64];
  __shared__ __attribute__((aligned(16))) u16 T2s[64 * 72];
  __shared__ float betas[64];

  float4_ accG[4], accA[4];
#pragma unroll
  for (int ct = 0; ct < 4; ++ct) { accG[ct] = (float4_)0.f; accA[ct] = (float4_)0.f; }

  // phase A: G = K K^T, Araw = Q K^T  (K-streamed)
  for (int kk = 0; kk < DD; kk += 64) {
#pragma unroll
    for (int i = 0; i < 2; ++i) {
      int e = tid + 256 * i;
      int row = e >> 3, col = (e & 7) * 8;
      *(short8*)&Kt[row * 64 + col] = *(const short8*)(K + (row0 + row) * DD + kk + col);
      *(short8*)&Qt[row * 64 + col] = *(const short8*)(Q + (row0 + row) * DD + kk + col);
    }
    __syncthreads();
#pragma unroll
    for (int ks = 0; ks < 2; ++ks) {
      short8 ak = *(const short8*)&Kt[(16 * wv + (lane & 15)) * 64 + ks * 32 + (lane >> 4) * 8];
      short8 aq = *(const short8*)&Qt[(16 * wv + (lane & 15)) * 64 + ks * 32 + (lane >> 4) * 8];
#pragma unroll
      for (int ct = 0; ct < 4; ++ct) {
        short8 bk = *(const short8*)&Kt[(16 * ct + (lane & 15)) * 64 + ks * 32 + (lane >> 4) * 8];
        accG[ct] = mfma16(ak, bk, accG[ct]);
        accA[ct] = mfma16(aq, bk, accA[ct]);
      }
    }
    __syncthreads();
  }
  u16* Abase = Aout + (size_t)(b * NCH + ch) * (CC * CC);
#pragma unroll
  for (int ct = 0; ct < 4; ++ct) {
    int i0 = 16 * wv + ((lane >> 4) << 2);
    int c = 16 * ct + (lane & 15);
#pragma unroll
    for (int r = 0; r < 4; ++r) {
      int i = i0 + r;
      Gs[i * 65 + c] = accG[ct][r];
      Abase[i * 64 + c] = f2bf((c <= i) ? accA[ct][r] : 0.f);
    }
  }
  __syncthreads();
  if (tid < 64) betas[tid] = 1.f / (Gs[tid * 65 + tid] + 1e-6f);
  __syncthreads();
  for (int e = tid; e < 4096; e += 256) {
    int i = e >> 6, c = e & 63;
    Ts[i * 65 + c] = (c < i) ? (-betas[i] * Gs[i * 65 + c]) : 0.f;
  }
  __syncthreads();
  // forward substitution (reference exact recurrence)
  for (int i = 1; i < 64; ++i) {
    float rv = 0.f, acc = 0.f;
    if (tid < 64) {
      rv = Ts[i * 65 + tid];
      for (int j = 1; j < i; ++j) {
        float a = __shfl(rv, j);
        acc += a * Ts[j * 65 + tid];
      }
    }
    __syncthreads();
    if (tid < i) Ts[i * 65 + tid] = rv + acc;
    __syncthreads();
  }
  if (tid < 64) Ts[tid * 65 + tid] += 1.f;
  __syncthreads();
  for (int e = tid; e < 4096; e += 256) {   // T2[i][j] = T[i][j]*beta[j] (LDS only)
    int i = e >> 6, j = e & 63;
    T2s[i * 72 + j] = f2bf(Ts[i * 65 + j] * betas[j]);
  }
  __syncthreads();

  // phase B: U0 = T2 @ V (over V); W = T2 @ K -> Wall (all chunks); emit K^T -> KTg
  u16* KTs = (u16*)Gs;  // 64 x 72
  u16* VTs = (u16*)Ts;  // 64 x 72
  for (int kk = 0; kk < DD; kk += 64) {
#pragma unroll
    for (int rep = 0; rep < 2; ++rep) {   // transpose V and K tiles into LDS
      int t = tid >> 2;
      int c0 = (tid & 3) * 8 + rep * 32;
      short8 vv = *(const short8*)(V + (row0 + t) * DD + kk + c0);
      short8 vk = *(const short8*)(K + (row0 + t) * DD + kk + c0);
#pragma unroll
      for (int e = 0; e < 8; ++e) { VTs[(c0 + e) * 72 + t] = (u16)vv[e]; KTs[(c0 + e) * 72 + t] = (u16)vk[e]; }
    }
    __syncthreads();
    // emit K^T tile to global: KTg[(b, kk+jl, ch*64 + t)]
#pragma unroll
    for (int w2 = 0; w2 < 2; ++w2) {
      int e = tid + 256 * w2;
      int jl = e >> 3, toff = (e & 7) * 8;
      *(short8*)(KTg + ((size_t)b * DD + kk + jl) * LL + (size_t)ch * CC + toff) =
          *(const short8*)&KTs[jl * 72 + toff];
    }
    float4_ accU[4], accW[4];
#pragma unroll
    for (int ct = 0; ct < 4; ++ct) { accU[ct] = (float4_)0.f; accW[ct] = (float4_)0.f; }
#pragma unroll
    for (int ks = 0; ks < 2; ++ks) {
      short8 a2 = *(const short8*)&T2s[(16 * wv + (lane & 15)) * 72 + ks * 32 + (lane >> 4) * 8];
#pragma unroll
      for (int ct = 0; ct < 4; ++ct) {
        short8 bu = *(const short8*)&VTs[(16 * ct + (lane & 15)) * 72 + ks * 32 + (lane >> 4) * 8];
        short8 bw = *(const short8*)&KTs[(16 * ct + (lane & 15)) * 72 + ks * 32 + (lane >> 4) * 8];
        accU[ct] = mfma16(a2, bu, accU[ct]);
        accW[ct] = mfma16(a2, bw, accW[ct]);
      }
    }
#pragma unroll
    for (int ct = 0; ct < 4; ++ct) {
      int i0 = 16 * wv + ((lane >> 4) << 2);
      int c = kk + 16 * ct + (lane & 15);
#pragma unroll
      for (int r = 0; r < 4; ++r) {
        V[(row0 + i0 + r) * DD + c]    = f2bf(accU[ct][r]);   // U0 over V
        Wall[(row0 + i0 + r) * DD + c] = f2bf(accW[ct][r]);   // W for all chunks
      }
    }
    __syncthreads();
  }
}

// ---------------- fused scan: one persistent 256-thread WG per (b, 16-col slice of d_v) --------
// S^T[16][1028] f32 in static LDS (74.5 KB total -> 2 WGs/CU). 4 waves: j/dj slice 256 per wave.
// per chunk: phase1 u-=W@S, oq+=Q@S (atomic f32 reduce) | barrier | ub frags (cvt_pk)
// | barrier | phase3 S+=K^T@u, phase4 o=A@u+oq (owner wave zeroes oq), init next u_acc | barrier
__global__ __launch_bounds__(256, 1) void k_scan_fused(
    const u16* __restrict__ Q, const u16* __restrict__ Wg, const u16* __restrict__ KTg,
    const u16* __restrict__ U0, const u16* __restrict__ Ag, u16* __restrict__ Og) {
  __shared__ __attribute__((aligned(16))) float S[16 * 1028];     // 65792 B
  __shared__ __attribute__((aligned(16))) float u_acc[64 * 17];   //  4352 B
  __shared__ __attribute__((aligned(16))) float oq_acc[64 * 17];  //  4352 B -> 74496 total

  const int b = blockIdx.x & 7;               // XCD-affinity: batch b -> XCD b
  const int dc0 = (blockIdx.x >> 3) * 16;
  const int tid = threadIdx.x, lane = tid & 63, wv = tid >> 6;   // wv in 0..3
  const int r15 = lane & 15, hi = lane >> 4;  // hi in 0..3
  const int khi = hi * 8;
  const int tIq = tid >> 2, cIq = (tid & 3) * 4;   // 64 x 16 init coverage

  for (int i = tid; i < 16 * 1028; i += 256) S[i] = 0.f;
  {  // init u_acc = U0(ch0), oq_acc = 0
    us4 v = *(const us4*)(U0 + ((size_t)b * LL + tIq) * DD + dc0 + cIq);
#pragma unroll
    for (int e = 0; e < 4; ++e) {
      u_acc[tIq * 17 + cIq + e] = bf2f(v[e]);
      oq_acc[tIq * 17 + cIq + e] = 0.f;
    }
  }
  __syncthreads();

  for (int ch = 0; ch < NCH; ++ch) {
    const size_t row0 = (size_t)b * LL + (size_t)ch * CC;
    // ---- phase 1: wave wv covers j in [256*wv, 256*wv+256)
    {
      float4_ up[4], qp[4];
#pragma unroll
      for (int tt = 0; tt < 4; ++tt) { up[tt] = (float4_)0.f; qp[tt] = (float4_)0.f; }
#pragma unroll
      for (int ks = 0; ks < 8; ++ks) {
        const int j0 = wv * 256 + ks * 32 + khi;
        const float* sp = &S[r15 * 1028 + j0];
        float4_ x0 = *(const float4_*)sp;
        float4_ x1 = *(const float4_*)(sp + 4);
        S8U u;
        u.w[0] = cvtpk(x0[0], x0[1]);
        u.w[1] = cvtpk(x0[2], x0[3]);
        u.w[2] = cvtpk(x1[0], x1[1]);
        u.w[3] = cvtpk(x1[2], x1[3]);
        const short8 sf = u.s;
#pragma unroll
        for (int tt = 0; tt < 4; ++tt) {
          const size_t rbase = (row0 + tt * 16 + r15) * DD + j0;
          short8 wf = *(const short8*)(Wg + rbase);
          short8 qf = *(const short8*)(Q + rbase);
          up[tt] = mfma16(wf, sf, up[tt]);
          qp[tt] = mfma16(qf, sf, qp[tt]);
        }
      }
#pragma unroll
      for (int tt = 0; tt < 4; ++tt) {
        const int t0 = tt * 16 + hi * 4;
#pragma unroll
        for (int r = 0; r < 4; ++r) {
          atomicAdd(&u_acc[(t0 + r) * 17 + r15], -up[tt][r]);
          atomicAdd(&oq_acc[(t0 + r) * 17 + r15], qp[tt][r]);
        }
      }
    }
    __syncthreads();   // barrier A: u/oq reductions complete
    // ---- build ub frags straight from f32 u_acc (cvt_pk)
    short8 ub[2];
#pragma unroll
    for (int ks2 = 0; ks2 < 2; ++ks2) {
      S8U u;
#pragma unroll
      for (int w2 = 0; w2 < 4; ++w2) {
        float lo = u_acc[(ks2 * 32 + khi + 2 * w2) * 17 + r15];
        float h2 = u_acc[(ks2 * 32 + khi + 2 * w2 + 1) * 17 + r15];
        u.w[w2] = cvtpk(lo, h2);
      }
      ub[ks2] = u.s;
    }
    __syncthreads();   // barrier B: ub reads done before u_acc re-init below
    // ---- phase 3: S[dc][dj] += sum_t u[t,dc] K[t,dj], wave wv's 256-wide dj slice
    {
      const size_t ktb = ((size_t)b * DD) * LL + (size_t)ch * CC;
#pragma unroll 4
      for (int djt = 0; djt < 16; ++djt) {
        const int dj0 = wv * 256 + djt * 16;
        short8 kf0 = *(const short8*)(KTg + ktb + (size_t)(dj0 + r15) * LL + khi);
        short8 kf1 = *(const short8*)(KTg + ktb + (size_t)(dj0 + r15) * LL + 32 + khi);
        float* sp = &S[r15 * 1028 + dj0 + hi * 4];
        float4_ c = *(const float4_*)sp;
        c = mfma16(kf0, ub[0], c);
        c = mfma16(kf1, ub[1], c);
        *(float4_*)sp = c;
      }
      // ---- phase 4: o = A@u + oq -> Og; wave wv owns t-tile wv; zero oq after read
      const u16* Ab = Ag + (size_t)(b * NCH + ch) * (CC * CC);
      short8 af0 = *(const short8*)(Ab + (wv * 16 + r15) * CC + khi);
      short8 af1 = *(const short8*)(Ab + (wv * 16 + r15) * CC + 32 + khi);
      const int t0 = wv * 16 + hi * 4;
      float4_ c;
#pragma unroll
      for (int r = 0; r < 4; ++r) { c[r] = oq_acc[(t0 + r) * 17 + r15]; oq_acc[(t0 + r) * 17 + r15] = 0.f; }
      c = mfma16(af0, ub[0], c);
      c = mfma16(af1, ub[1], c);
#pragma unroll
      for (int r = 0; r < 4; ++r)
        Og[(row0 + t0 + r) * DD + dc0 + r15] = f2bf(c[r]);
      // ---- init u_acc for next chunk (u_acc free after barrier B)
      if (ch + 1 < NCH) {
        us4 v = *(const us4*)(U0 + (row0 + CC + tIq) * DD + dc0 + cIq);
#pragma unroll
        for (int e = 0; e < 4; ++e) u_acc[tIq * 17 + cIq + e] = bf2f(v[e]);
      }
    }
    __syncthreads();   // barrier C: S/oq/u_acc consistent for next chunk
  }
}

extern "C" void kernel_launch(void* const* d_in, const int* in_sizes, int n_in,
                              void* d_out, int out_size, void* d_ws, size_t ws_size,
                              hipStream_t stream) {
  (void)in_sizes; (void)n_in; (void)out_size; (void)ws_size;
  const void* X  = d_in[0];
  // d_in[1] = chunk (=64), hard-coded
  const void* Wq = d_in[2]; const void* bq = d_in[3];
  const void* Wk = d_in[4]; const void* bk = d_in[5];
  const void* Wv = d_in[6]; const void* bv = d_in[7];
  const void* Wo = d_in[8]; const void* bo = d_in[9];

  char* ws = (char*)d_ws;
  int* flag = (int*)ws;
  char* p = ws + 256;
  const size_t E2 = (size_t)NB * LL * DD * 2;                  // 64 MiB per bf16 (B,L,D)
  u16* xb   = (u16*)p; p += E2;                                // X bf16; K^T (B,D,L) overlays after QKV
  u16* kt   = xb;
  u16* wqb  = (u16*)p; p += (size_t)DD * DD * 2;
  u16* wkb  = (u16*)p; p += (size_t)DD * DD * 2;
  u16* wvb  = (u16*)p; p += (size_t)DD * DD * 2;
  u16* wob  = (u16*)p; p += (size_t)DD * DD * 2;
  u16* bqb  = (u16*)p; p += 4096;
  u16* bkb  = (u16*)p; p += 4096;
  u16* bvb  = (u16*)p; p += 4096;
  u16* bob  = (u16*)p; p += 4096;
  u16* q_ws = (u16*)p; p += E2;                                // Q
  u16* k_ws = (u16*)p; p += E2;                                // K; scan writes o (Opre) here
  u16* v_ws = (u16*)p; p += E2;                                // V -> U0 in place
  u16* a_ws = (u16*)p; p += (size_t)NB * NCH * CC * CC * 2;    // 4 MiB
  u16* w_all = (u16*)p; p += E2;                               // W = T2@K for all chunks
  // total ~268 MiB

  k_detect<<<1, 64, 0, stream>>>((const uint32_t*)X, flag);
  const long nX = (long)NB * LL * DD / 8;
  k_convert<<<(nX + 255) / 256, 256, 0, stream>>>(X, xb, nX, flag);
  const long nW = (long)DD * DD / 8;
  k_convert<<<(nW + 255) / 256, 256, 0, stream>>>(Wq, wqb, nW, flag);
  k_convert<<<(nW + 255) / 256, 256, 0, stream>>>(Wk, wkb, nW, flag);
  k_convert<<<(nW + 255) / 256, 256, 0, stream>>>(Wv, wvb, nW, flag);
  k_convert<<<(nW + 255) / 256, 256, 0, stream>>>(Wo, wob, nW, flag);
  const long nBias = DD / 8;
  k_convert<<<1, 256, 0, stream>>>(bq, bqb, nBias, flag);
  k_convert<<<1, 256, 0, stream>>>(bk, bkb, nBias, flag);
  k_convert<<<1, 256, 0, stream>>>(bv, bvb, nBias, flag);
  k_convert<<<1, 256, 0, stream>>>(bo, bob, nBias, flag);

  k_gemm_qkv<<<dim3(24, 256), 256, 0, stream>>>(xb, wqb, bqb, wkb, bkb, wvb, bvb, q_ws, k_ws, v_ws);
  k_prep<<<dim3(64, 8), 256, 0, stream>>>(q_ws, k_ws, v_ws, a_ws, w_all, kt);
  k_scan_fused<<<dim3(512), 256, 0, stream>>>(q_ws, w_all, kt, v_ws, a_ws, k_ws);
  k_gemm_o<<<dim3(8, 256), 256, 0, stream>>>(k_ws, wob, bob, d_out, flag);
}

// Round 5
// 3258.271 us; speedup vs baseline: 1.3494x; 1.0194x over previous
//
#include <hip/hip_runtime.h>
#include <stdint.h>

typedef unsigned short u16;
typedef __attribute__((ext_vector_type(8))) short short8;     // 8 bf16 (MFMA A/B frag)
typedef __attribute__((ext_vector_type(4))) float float4_;    // MFMA C/D frag
typedef __attribute__((ext_vector_type(4))) unsigned short us4;

#define NB 8
#define LL 4096
#define DD 1024
#define CC 64
#define NCH 64   // LL/CC

__device__ __forceinline__ u16 f2bf(float f) {
  union { float f; uint32_t u; } v; v.f = f;
  uint32_t u = v.u;
  return (u16)((u + 0x7fffu + ((u >> 16) & 1u)) >> 16);   // RNE
}
__device__ __forceinline__ float bf2f(u16 h) {
  union { uint32_t u; float f; } v; v.u = ((uint32_t)h) << 16;
  return v.f;
}
__device__ __forceinline__ float4_ mfma16(short8 a, short8 b, float4_ c) {
  return __builtin_amdgcn_mfma_f32_16x16x32_bf16(a, b, c, 0, 0, 0);
}
// packed f32x2 -> bf16x2, RNE (same rounding as f2bf)
__device__ __forceinline__ uint32_t cvtpk(float lo, float hi) {
  uint32_t r;
  asm("v_cvt_pk_bf16_f32 %0, %1, %2" : "=v"(r) : "v"(lo), "v"(hi));
  return r;
}
union S8U { short8 s; uint32_t w[4]; };

// ---------------- dtype detect: flag=1 if inputs are bf16, 0 if f32 ----------------
__global__ void k_detect(const uint32_t* __restrict__ X, int* __restrict__ flag) {
  if (threadIdx.x == 0 && blockIdx.x == 0) {
    int votes = 0;
    for (int i = 0; i < 64; ++i) {
      uint32_t w = X[i];
      uint32_t e = (w >> 7) & 0xFF;   // exponent field of the LOW u16 viewed as bf16
      votes += (e > 134 || e < 110) ? 1 : 0;
    }
    *flag = (votes < 8) ? 1 : 0;
  }
}

// ---------------- convert input tensor -> bf16 (dual dtype) ----------------
__global__ __launch_bounds__(256) void k_convert(const void* __restrict__ src, u16* __restrict__ dst,
                                                 long n8, const int* __restrict__ flag) {
  long i = (long)blockIdx.x * 256 + threadIdx.x;   // index of 8-element chunk
  if (i >= n8) return;
  if (*flag) {
    ((short8*)dst)[i] = ((const short8*)src)[i];
  } else {
    const float4_* s = (const float4_*)src;
    float4_ a = s[2 * i], b = s[2 * i + 1];
    short8 o;
#pragma unroll
    for (int j = 0; j < 4; ++j) { o[j] = (short)f2bf(a[j]); o[4 + j] = (short)f2bf(b[j]); }
    ((short8*)dst)[i] = o;
  }
}

// ---------------- big NT GEMM: Out(M x 1024) = A(M x 1024) @ W(1024 x 1024)^T + bias ----------------
template <bool DUAL>
__device__ __forceinline__ void gemm128(const u16* __restrict__ A, const u16* __restrict__ W,
                                        const u16* __restrict__ bias, void* __restrict__ Out,
                                        int m0, int n0, const int* __restrict__ flag) {
  __shared__ __attribute__((aligned(16))) u16 As[128 * 64];
  __shared__ __attribute__((aligned(16))) u16 Bs[128 * 64];
  const int tid = threadIdx.x, lane = tid & 63, wv = tid >> 6;
  float4_ acc[2][8];
#pragma unroll
  for (int i = 0; i < 2; ++i)
#pragma unroll
    for (int j = 0; j < 8; ++j) acc[i][j] = (float4_)0.f;

  for (int kk = 0; kk < DD; kk += 64) {
#pragma unroll
    for (int i = 0; i < 4; ++i) {
      int e = tid + 256 * i;
      int row = e >> 3, col = (e & 7) * 8;
      *(short8*)&As[row * 64 + col] = *(const short8*)(A + (size_t)(m0 + row) * DD + kk + col);
      *(short8*)&Bs[row * 64 + col] = *(const short8*)(W + (size_t)(n0 + row) * DD + kk + col);
    }
    __syncthreads();
#pragma unroll
    for (int ks = 0; ks < 2; ++ks) {
      short8 af[2];
#pragma unroll
      for (int mt = 0; mt < 2; ++mt)
        af[mt] = *(const short8*)&As[(32 * wv + 16 * mt + (lane & 15)) * 64 + ks * 32 + (lane >> 4) * 8];
#pragma unroll
      for (int nt = 0; nt < 8; ++nt) {
        short8 bf = *(const short8*)&Bs[(16 * nt + (lane & 15)) * 64 + ks * 32 + (lane >> 4) * 8];
#pragma unroll
        for (int mt = 0; mt < 2; ++mt) acc[mt][nt] = mfma16(af[mt], bf, acc[mt][nt]);
      }
    }
    __syncthreads();
  }
  const bool obf = DUAL ? (*flag != 0) : true;
#pragma unroll
  for (int mt = 0; mt < 2; ++mt)
#pragma unroll
    for (int nt = 0; nt < 8; ++nt) {
      int rg = m0 + 32 * wv + 16 * mt + ((lane >> 4) << 2);
      int cg = n0 + 16 * nt + (lane & 15);
      float bv = bf2f(bias[cg]);
#pragma unroll
      for (int r = 0; r < 4; ++r) {
        float o = acc[mt][nt][r] + bv;
        if (obf) ((u16*)Out)[(size_t)(rg + r) * DD + cg] = f2bf(o);
        else     ((float*)Out)[(size_t)(rg + r) * DD + cg] = o;
      }
    }
}

__global__ __launch_bounds__(256) void k_gemm_qkv(const u16* __restrict__ X,
    const u16* __restrict__ Wq, const u16* __restrict__ bq,
    const u16* __restrict__ Wk, const u16* __restrict__ bk,
    const u16* __restrict__ Wv, const u16* __restrict__ bv,
    u16* __restrict__ Qo, u16* __restrict__ Ko, u16* __restrict__ Vo) {
  int nb = blockIdx.x;  // 0..23
  int mat = nb >> 3, nt = nb & 7;
  const u16 *W, *bi; u16* O;
  if (mat == 0)      { W = Wq; bi = bq; O = Qo; }
  else if (mat == 1) { W = Wk; bi = bk; O = Ko; }
  else               { W = Wv; bi = bv; O = Vo; }
  gemm128<false>(X, W, bi, O, blockIdx.y * 128, nt * 128, nullptr);
}

__global__ __launch_bounds__(256) void k_gemm_o(const u16* __restrict__ A,
    const u16* __restrict__ Wo, const u16* __restrict__ bo, void* __restrict__ Out,
    const int* __restrict__ flag) {
  gemm128<true>(A, Wo, bo, Out, blockIdx.y * 128, blockIdx.x * 128, flag);
}

// ---------------- prep: per (chunk, batch): beta, T2, U0 (over V), A=tril(QK^T),
//                  W = T2@K (ALL chunks) -> Wall, and K^T emission -> KTg (B,D,L) ----------------
__global__ __launch_bounds__(256) void k_prep(const u16* __restrict__ Q, const u16* __restrict__ K,
                                              u16* __restrict__ V /* V in, U0 out (in place) */,
                                              u16* __restrict__ Aout, u16* __restrict__ Wall,
                                              u16* __restrict__ KTg) {
  const int ch = blockIdx.x, b = blockIdx.y;
  const size_t row0 = (size_t)b * LL + (size_t)ch * CC;
  const int tid = threadIdx.x, lane = tid & 63, wv = tid >> 6;

  __shared__ __attribute__((aligned(16))) float Gs[64 * 65];   // reused as KTs (u16 64x72) in phase B
  __shared__ __attribute__((aligned(16))) float Ts[64 * 65];   // reused as VTs (u16 64x72) in phase B
  __shared__ __attribute__((aligned(16))) u16 Kt[64 * 64];
  __shared__ __attribute__((aligned(16))) u16 Qt[64 * 64];
  __shared__ __attribute__((aligned(16))) u16 T2s[64 * 72];
  __shared__ float betas[64];

  float4_ accG[4], accA[4];
#pragma unroll
  for (int ct = 0; ct < 4; ++ct) { accG[ct] = (float4_)0.f; accA[ct] = (float4_)0.f; }

  // phase A: G = K K^T, Araw = Q K^T  (K-streamed)
  for (int kk = 0; kk < DD; kk += 64) {
#pragma unroll
    for (int i = 0; i < 2; ++i) {
      int e = tid + 256 * i;
      int row = e >> 3, col = (e & 7) * 8;
      *(short8*)&Kt[row * 64 + col] = *(const short8*)(K + (row0 + row) * DD + kk + col);
      *(short8*)&Qt[row * 64 + col] = *(const short8*)(Q + (row0 + row) * DD + kk + col);
    }
    __syncthreads();
#pragma unroll
    for (int ks = 0; ks < 2; ++ks) {
      short8 ak = *(const short8*)&Kt[(16 * wv + (lane & 15)) * 64 + ks * 32 + (lane >> 4) * 8];
      short8 aq = *(const short8*)&Qt[(16 * wv + (lane & 15)) * 64 + ks * 32 + (lane >> 4) * 8];
#pragma unroll
      for (int ct = 0; ct < 4; ++ct) {
        short8 bk = *(const short8*)&Kt[(16 * ct + (lane & 15)) * 64 + ks * 32 + (lane >> 4) * 8];
        accG[ct] = mfma16(ak, bk, accG[ct]);
        accA[ct] = mfma16(aq, bk, accA[ct]);
      }
    }
    __syncthreads();
  }
  u16* Abase = Aout + (size_t)(b * NCH + ch) * (CC * CC);
#pragma unroll
  for (int ct = 0; ct < 4; ++ct) {
    int i0 = 16 * wv + ((lane >> 4) << 2);
    int c = 16 * ct + (lane & 15);
#pragma unroll
    for (int r = 0; r < 4; ++r) {
      int i = i0 + r;
      Gs[i * 65 + c] = accG[ct][r];
      Abase[i * 64 + c] = f2bf((c <= i) ? accA[ct][r] : 0.f);
    }
  }
  __syncthreads();
  if (tid < 64) betas[tid] = 1.f / (Gs[tid * 65 + tid] + 1e-6f);
  __syncthreads();
  for (int e = tid; e < 4096; e += 256) {
    int i = e >> 6, c = e & 63;
    Ts[i * 65 + c] = (c < i) ? (-betas[i] * Gs[i * 65 + c]) : 0.f;
  }
  __syncthreads();
  // forward substitution (reference exact recurrence)
  for (int i = 1; i < 64; ++i) {
    float rv = 0.f, acc = 0.f;
    if (tid < 64) {
      rv = Ts[i * 65 + tid];
      for (int j = 1; j < i; ++j) {
        float a = __shfl(rv, j);
        acc += a * Ts[j * 65 + tid];
      }
    }
    __syncthreads();
    if (tid < i) Ts[i * 65 + tid] = rv + acc;
    __syncthreads();
  }
  if (tid < 64) Ts[tid * 65 + tid] += 1.f;
  __syncthreads();
  for (int e = tid; e < 4096; e += 256) {   // T2[i][j] = T[i][j]*beta[j] (LDS only)
    int i = e >> 6, j = e & 63;
    T2s[i * 72 + j] = f2bf(Ts[i * 65 + j] * betas[j]);
  }
  __syncthreads();

  // phase B: U0 = T2 @ V (over V); W = T2 @ K -> Wall (all chunks); emit K^T -> KTg
  u16* KTs = (u16*)Gs;  // 64 x 72
  u16* VTs = (u16*)Ts;  // 64 x 72
  for (int kk = 0; kk < DD; kk += 64) {
#pragma unroll
    for (int rep = 0; rep < 2; ++rep) {   // transpose V and K tiles into LDS
      int t = tid >> 2;
      int c0 = (tid & 3) * 8 + rep * 32;
      short8 vv = *(const short8*)(V + (row0 + t) * DD + kk + c0);
      short8 vk = *(const short8*)(K + (row0 + t) * DD + kk + c0);
#pragma unroll
      for (int e = 0; e < 8; ++e) { VTs[(c0 + e) * 72 + t] = (u16)vv[e]; KTs[(c0 + e) * 72 + t] = (u16)vk[e]; }
    }
    __syncthreads();
    // emit K^T tile to global: KTg[(b, kk+jl, ch*64 + t)]
#pragma unroll
    for (int w2 = 0; w2 < 2; ++w2) {
      int e = tid + 256 * w2;
      int jl = e >> 3, toff = (e & 7) * 8;
      *(short8*)(KTg + ((size_t)b * DD + kk + jl) * LL + (size_t)ch * CC + toff) =
          *(const short8*)&KTs[jl * 72 + toff];
    }
    float4_ accU[4], accW[4];
#pragma unroll
    for (int ct = 0; ct < 4; ++ct) { accU[ct] = (float4_)0.f; accW[ct] = (float4_)0.f; }
#pragma unroll
    for (int ks = 0; ks < 2; ++ks) {
      short8 a2 = *(const short8*)&T2s[(16 * wv + (lane & 15)) * 72 + ks * 32 + (lane >> 4) * 8];
#pragma unroll
      for (int ct = 0; ct < 4; ++ct) {
        short8 bu = *(const short8*)&VTs[(16 * ct + (lane & 15)) * 72 + ks * 32 + (lane >> 4) * 8];
        short8 bw = *(const short8*)&KTs[(16 * ct + (lane & 15)) * 72 + ks * 32 + (lane >> 4) * 8];
        accU[ct] = mfma16(a2, bu, accU[ct]);
        accW[ct] = mfma16(a2, bw, accW[ct]);
      }
    }
#pragma unroll
    for (int ct = 0; ct < 4; ++ct) {
      int i0 = 16 * wv + ((lane >> 4) << 2);
      int c = kk + 16 * ct + (lane & 15);
#pragma unroll
      for (int r = 0; r < 4; ++r) {
        V[(row0 + i0 + r) * DD + c]    = f2bf(accU[ct][r]);   // U0 over V
        Wall[(row0 + i0 + r) * DD + c] = f2bf(accW[ct][r]);   // W for all chunks
      }
    }
    __syncthreads();
  }
}

// ---------------- fused scan: one persistent 256-thread WG per (b, 16-col slice of d_v) --------
// S^T[16][1028] f32 in static LDS (74.5 KB total -> 2 WGs/CU). 4 waves: j/dj slice 256 per wave.
// Register-pipelined loads (2-stage) + cross-chunk L2 warming of W/Q/KT slabs.
__global__ __launch_bounds__(256, 2) void k_scan_fused(
    const u16* __restrict__ Q, const u16* __restrict__ Wg, const u16* __restrict__ KTg,
    const u16* __restrict__ U0, const u16* __restrict__ Ag, u16* __restrict__ Og) {
  __shared__ __attribute__((aligned(16))) float S[16 * 1028];     // 65792 B
  __shared__ __attribute__((aligned(16))) float u_acc[64 * 17];   //  4352 B
  __shared__ __attribute__((aligned(16))) float oq_acc[64 * 17];  //  4352 B -> 74496 total

  const int b = blockIdx.x & 7;               // XCD-affinity: batch b -> XCD b
  const int sc = blockIdx.x >> 3;             // slice index 0..63 (also warming slice)
  const int dc0 = sc * 16;
  const int tid = threadIdx.x, lane = tid & 63, wv = tid >> 6;   // wv in 0..3
  const int r15 = lane & 15, hi = lane >> 4;  // hi in 0..3
  const int khi = hi * 8;
  const int tIq = tid >> 2, cIq = (tid & 3) * 4;   // 64 x 16 init coverage

  for (int i = tid; i < 16 * 1028; i += 256) S[i] = 0.f;
  {  // init u_acc = U0(ch0), oq_acc = 0
    us4 v = *(const us4*)(U0 + ((size_t)b * LL + tIq) * DD + dc0 + cIq);
#pragma unroll
    for (int e = 0; e < 4; ++e) {
      u_acc[tIq * 17 + cIq + e] = bf2f(v[e]);
      oq_acc[tIq * 17 + cIq + e] = 0.f;
    }
  }
  __syncthreads();

  for (int ch = 0; ch < NCH; ++ch) {
    const size_t row0 = (size_t)b * LL + (size_t)ch * CC;
    // ---- L2 warming for chunk ch+1: this WG covers slice sc of each slab.
    // Kept live via asm sink (prevents DCE); values unused.
    if (ch + 1 < NCH) {
      const size_t row0n = row0 + CC;
      if (tid < 128) {
        float4_ wm1 = *(const float4_*)(Wg + (row0n + sc) * DD + tid * 8);
        const size_t ktbn = (size_t)b * DD * LL + (size_t)(ch + 1) * CC;
        float4_ wm2 = *(const float4_*)(KTg + ktbn + (size_t)(sc * 16 + (tid >> 3)) * LL + (tid & 7) * 8);
        asm volatile("" :: "v"(wm1), "v"(wm2));
      } else {
        int l = tid - 128;
        float4_ wm3 = *(const float4_*)(Q + (row0n + sc) * DD + l * 8);
        asm volatile("" :: "v"(wm3));
      }
    }
    // ---- phase 1: wave wv covers j in [256*wv, 256*wv+256), 2-stage register pipeline
    {
      float4_ up[4], qp[4];
#pragma unroll
      for (int tt = 0; tt < 4; ++tt) { up[tt] = (float4_)0.f; qp[tt] = (float4_)0.f; }
      short8 wfb[2][4], qfb[2][4];
      float4_ sx[2][2];
      {  // prologue: loads for ks=0 into buffer 0
        const int j0 = wv * 256 + khi;
        const float* sp = &S[r15 * 1028 + j0];
        sx[0][0] = *(const float4_*)sp;
        sx[0][1] = *(const float4_*)(sp + 4);
#pragma unroll
        for (int tt = 0; tt < 4; ++tt) {
          const size_t rb = (row0 + tt * 16 + r15) * DD + j0;
          wfb[0][tt] = *(const short8*)(Wg + rb);
          qfb[0][tt] = *(const short8*)(Q + rb);
        }
      }
#pragma unroll
      for (int ks = 0; ks < 8; ++ks) {
        const int cur = ks & 1, nx = cur ^ 1;
        if (ks < 7) {  // issue ks+1 loads before consuming ks
          const int j1 = wv * 256 + (ks + 1) * 32 + khi;
          const float* spn = &S[r15 * 1028 + j1];
          sx[nx][0] = *(const float4_*)spn;
          sx[nx][1] = *(const float4_*)(spn + 4);
#pragma unroll
          for (int tt = 0; tt < 4; ++tt) {
            const size_t rb = (row0 + tt * 16 + r15) * DD + j1;
            wfb[nx][tt] = *(const short8*)(Wg + rb);
            qfb[nx][tt] = *(const short8*)(Q + rb);
          }
        }
        S8U u;
        u.w[0] = cvtpk(sx[cur][0][0], sx[cur][0][1]);
        u.w[1] = cvtpk(sx[cur][0][2], sx[cur][0][3]);
        u.w[2] = cvtpk(sx[cur][1][0], sx[cur][1][1]);
        u.w[3] = cvtpk(sx[cur][1][2], sx[cur][1][3]);
        const short8 sf = u.s;
#pragma unroll
        for (int tt = 0; tt < 4; ++tt) {
          up[tt] = mfma16(wfb[cur][tt], sf, up[tt]);
          qp[tt] = mfma16(qfb[cur][tt], sf, qp[tt]);
        }
      }
#pragma unroll
      for (int tt = 0; tt < 4; ++tt) {
        const int t0 = tt * 16 + hi * 4;
#pragma unroll
        for (int r = 0; r < 4; ++r) {
          atomicAdd(&u_acc[(t0 + r) * 17 + r15], -up[tt][r]);
          atomicAdd(&oq_acc[(t0 + r) * 17 + r15], qp[tt][r]);
        }
      }
    }
    __syncthreads();   // barrier A: u/oq reductions complete
    // ---- build ub frags straight from f32 u_acc (cvt_pk)
    short8 ub[2];
#pragma unroll
    for (int ks2 = 0; ks2 < 2; ++ks2) {
      S8U u;
#pragma unroll
      for (int w2 = 0; w2 < 4; ++w2) {
        float lo = u_acc[(ks2 * 32 + khi + 2 * w2) * 17 + r15];
        float h2 = u_acc[(ks2 * 32 + khi + 2 * w2 + 1) * 17 + r15];
        u.w[w2] = cvtpk(lo, h2);
      }
      ub[ks2] = u.s;
    }
    __syncthreads();   // barrier B: ub reads done before u_acc re-init below
    // ---- phase 3: S[dc][dj] += sum_t u[t,dc] K[t,dj]; 2-stage pipeline on kf loads
    {
      const size_t ktb = ((size_t)b * DD) * LL + (size_t)ch * CC;
      short8 kb[2][2];
      {  // prologue djt=0
        const int dj0 = wv * 256;
        kb[0][0] = *(const short8*)(KTg + ktb + (size_t)(dj0 + r15) * LL + khi);
        kb[0][1] = *(const short8*)(KTg + ktb + (size_t)(dj0 + r15) * LL + 32 + khi);
      }
#pragma unroll
      for (int djt = 0; djt < 16; ++djt) {
        const int cur = djt & 1, nx = cur ^ 1;
        if (djt < 15) {
          const int dj1 = wv * 256 + (djt + 1) * 16;
          kb[nx][0] = *(const short8*)(KTg + ktb + (size_t)(dj1 + r15) * LL + khi);
          kb[nx][1] = *(const short8*)(KTg + ktb + (size_t)(dj1 + r15) * LL + 32 + khi);
        }
        const int dj0 = wv * 256 + djt * 16;
        float* sp = &S[r15 * 1028 + dj0 + hi * 4];
        float4_ c = *(const float4_*)sp;
        c = mfma16(kb[cur][0], ub[0], c);
        c = mfma16(kb[cur][1], ub[1], c);
        *(float4_*)sp = c;
      }
      // ---- phase 4: o = A@u + oq -> Og; wave wv owns t-tile wv; zero oq after read
      const u16* Ab = Ag + (size_t)(b * NCH + ch) * (CC * CC);
      short8 af0 = *(const short8*)(Ab + (wv * 16 + r15) * CC + khi);
      short8 af1 = *(const short8*)(Ab + (wv * 16 + r15) * CC + 32 + khi);
      const int t0 = wv * 16 + hi * 4;
      float4_ c;
#pragma unroll
      for (int r = 0; r < 4; ++r) { c[r] = oq_acc[(t0 + r) * 17 + r15]; oq_acc[(t0 + r) * 17 + r15] = 0.f; }
      c = mfma16(af0, ub[0], c);
      c = mfma16(af1, ub[1], c);
#pragma unroll
      for (int r = 0; r < 4; ++r)
        Og[(row0 + t0 + r) * DD + dc0 + r15] = f2bf(c[r]);
      // ---- init u_acc for next chunk (u_acc free after barrier B)
      if (ch + 1 < NCH) {
        us4 v = *(const us4*)(U0 + (row0 + CC + tIq) * DD + dc0 + cIq);
#pragma unroll
        for (int e = 0; e < 4; ++e) u_acc[tIq * 17 + cIq + e] = bf2f(v[e]);
      }
    }
    __syncthreads();   // barrier C: S/oq/u_acc consistent for next chunk
  }
}

extern "C" void kernel_launch(void* const* d_in, const int* in_sizes, int n_in,
                              void* d_out, int out_size, void* d_ws, size_t ws_size,
                              hipStream_t stream) {
  (void)in_sizes; (void)n_in; (void)out_size; (void)ws_size;
  const void* X  = d_in[0];
  // d_in[1] = chunk (=64), hard-coded
  const void* Wq = d_in[2]; const void* bq = d_in[3];
  const void* Wk = d_in[4]; const void* bk = d_in[5];
  const void* Wv = d_in[6]; const void* bv = d_in[7];
  const void* Wo = d_in[8]; const void* bo = d_in[9];

  char* ws = (char*)d_ws;
  int* flag = (int*)ws;
  char* p = ws + 256;
  const size_t E2 = (size_t)NB * LL * DD * 2;                  // 64 MiB per bf16 (B,L,D)
  u16* xb   = (u16*)p; p += E2;                                // X bf16; K^T (B,D,L) overlays after QKV
  u16* kt   = xb;
  u16* wqb  = (u16*)p; p += (size_t)DD * DD * 2;
  u16* wkb  = (u16*)p; p += (size_t)DD * DD * 2;
  u16* wvb  = (u16*)p; p += (size_t)DD * DD * 2;
  u16* wob  = (u16*)p; p += (size_t)DD * DD * 2;
  u16* bqb  = (u16*)p; p += 4096;
  u16* bkb  = (u16*)p; p += 4096;
  u16* bvb  = (u16*)p; p += 4096;
  u16* bob  = (u16*)p; p += 4096;
  u16* q_ws = (u16*)p; p += E2;                                // Q
  u16* k_ws = (u16*)p; p += E2;                                // K; scan writes o (Opre) here
  u16* v_ws = (u16*)p; p += E2;                                // V -> U0 in place
  u16* a_ws = (u16*)p; p += (size_t)NB * NCH * CC * CC * 2;    // 4 MiB
  u16* w_all = (u16*)p; p += E2;                               // W = T2@K for all chunks
  // total ~268 MiB

  k_detect<<<1, 64, 0, stream>>>((const uint32_t*)X, flag);
  const long nX = (long)NB * LL * DD / 8;
  k_convert<<<(nX + 255) / 256, 256, 0, stream>>>(X, xb, nX, flag);
  const long nW = (long)DD * DD / 8;
  k_convert<<<(nW + 255) / 256, 256, 0, stream>>>(Wq, wqb, nW, flag);
  k_convert<<<(nW + 255) / 256, 256, 0, stream>>>(Wk, wkb, nW, flag);
  k_convert<<<(nW + 255) / 256, 256, 0, stream>>>(Wv, wvb, nW, flag);
  k_convert<<<(nW + 255) / 256, 256, 0, stream>>>(Wo, wob, nW, flag);
  const long nBias = DD / 8;
  k_convert<<<1, 256, 0, stream>>>(bq, bqb, nBias, flag);
  k_convert<<<1, 256, 0, stream>>>(bk, bkb, nBias, flag);
  k_convert<<<1, 256, 0, stream>>>(bv, bvb, nBias, flag);
  k_convert<<<1, 256, 0, stream>>>(bo, bob, nBias, flag);

  k_gemm_qkv<<<dim3(24, 256), 256, 0, stream>>>(xb, wqb, bqb, wkb, bkb, wvb, bvb, q_ws, k_ws, v_ws);
  k_prep<<<dim3(64, 8), 256, 0, stream>>>(q_ws, k_ws, v_ws, a_ws, w_all, kt);
  k_scan_fused<<<dim3(512), 256, 0, stream>>>(q_ws, w_all, kt, v_ws, a_ws, k_ws);
  k_gemm_o<<<dim3(8, 256), 256, 0, stream>>>(k_ws, wob, bob, d_out, flag);
}

// Round 6
// 2604.290 us; speedup vs baseline: 1.6882x; 1.2511x over previous
//
#include <hip/hip_runtime.h>
#include <stdint.h>

typedef unsigned short u16;
typedef __attribute__((ext_vector_type(8))) short short8;     // 8 bf16 (MFMA A/B frag)
typedef __attribute__((ext_vector_type(4))) float float4_;    // MFMA C/D frag

#define NB 8
#define LL 4096
#define DD 1024
#define CC 64
#define NCH 64   // LL/CC

__device__ __forceinline__ u16 f2bf(float f) {
  union { float f; uint32_t u; } v; v.f = f;
  uint32_t u = v.u;
  return (u16)((u + 0x7fffu + ((u >> 16) & 1u)) >> 16);   // RNE
}
__device__ __forceinline__ float bf2f(u16 h) {
  union { uint32_t u; float f; } v; v.u = ((uint32_t)h) << 16;
  return v.f;
}
__device__ __forceinline__ float4_ mfma16(short8 a, short8 b, float4_ c) {
  return __builtin_amdgcn_mfma_f32_16x16x32_bf16(a, b, c, 0, 0, 0);
}
// packed f32x2 -> bf16x2, RNE (same rounding as f2bf)
__device__ __forceinline__ uint32_t cvtpk(float lo, float hi) {
  uint32_t r;
  asm("v_cvt_pk_bf16_f32 %0, %1, %2" : "=v"(r) : "v"(lo), "v"(hi));
  return r;
}
union S8U { short8 s; uint32_t w[4]; };

// async global->LDS DMA, 16B per lane. lds ptr must be wave-uniform base (lane*16 auto).
__device__ __forceinline__ void gld_lds16(const u16* g, u16* l) {
  __builtin_amdgcn_global_load_lds(
      (const __attribute__((address_space(1))) uint32_t*)g,
      (__attribute__((address_space(3))) uint32_t*)l, 16, 0, 0);
}

// ---------------- dtype detect: flag=1 if inputs are bf16, 0 if f32 ----------------
__global__ void k_detect(const uint32_t* __restrict__ X, int* __restrict__ flag) {
  if (threadIdx.x == 0 && blockIdx.x == 0) {
    int votes = 0;
    for (int i = 0; i < 64; ++i) {
      uint32_t w = X[i];
      uint32_t e = (w >> 7) & 0xFF;
      votes += (e > 134 || e < 110) ? 1 : 0;
    }
    *flag = (votes < 8) ? 1 : 0;
  }
}

// ---------------- convert input tensor -> bf16 (dual dtype) ----------------
__global__ __launch_bounds__(256) void k_convert(const void* __restrict__ src, u16* __restrict__ dst,
                                                 long n8, const int* __restrict__ flag) {
  long i = (long)blockIdx.x * 256 + threadIdx.x;
  if (i >= n8) return;
  if (*flag) {
    ((short8*)dst)[i] = ((const short8*)src)[i];
  } else {
    const float4_* s = (const float4_*)src;
    float4_ a = s[2 * i], b = s[2 * i + 1];
    short8 o;
#pragma unroll
    for (int j = 0; j < 4; ++j) { o[j] = (short)f2bf(a[j]); o[4 + j] = (short)f2bf(b[j]); }
    ((short8*)dst)[i] = o;
  }
}

// ---------------- big NT GEMM: Out(M x 1024) = A(M x 1024) @ W(1024 x 1024)^T + bias -------------
// OM: 0 = row-major bf16 out, 1 = dual (flag-keyed bf16/f32), 2 = 64x64-tiled bf16 out
template <int OM>
__device__ __forceinline__ void gemm128(const u16* __restrict__ A, const u16* __restrict__ W,
                                        const u16* __restrict__ bias, void* __restrict__ Out,
                                        int m0, int n0, const int* __restrict__ flag) {
  __shared__ __attribute__((aligned(16))) u16 As[128 * 64];
  __shared__ __attribute__((aligned(16))) u16 Bs[128 * 64];
  const int tid = threadIdx.x, lane = tid & 63, wv = tid >> 6;
  float4_ acc[2][8];
#pragma unroll
  for (int i = 0; i < 2; ++i)
#pragma unroll
    for (int j = 0; j < 8; ++j) acc[i][j] = (float4_)0.f;

  for (int kk = 0; kk < DD; kk += 64) {
#pragma unroll
    for (int i = 0; i < 4; ++i) {
      int e = tid + 256 * i;
      int row = e >> 3, col = (e & 7) * 8;
      *(short8*)&As[row * 64 + col] = *(const short8*)(A + (size_t)(m0 + row) * DD + kk + col);
      *(short8*)&Bs[row * 64 + col] = *(const short8*)(W + (size_t)(n0 + row) * DD + kk + col);
    }
    __syncthreads();
#pragma unroll
    for (int ks = 0; ks < 2; ++ks) {
      short8 af[2];
#pragma unroll
      for (int mt = 0; mt < 2; ++mt)
        af[mt] = *(const short8*)&As[(32 * wv + 16 * mt + (lane & 15)) * 64 + ks * 32 + (lane >> 4) * 8];
#pragma unroll
      for (int nt = 0; nt < 8; ++nt) {
        short8 bf = *(const short8*)&Bs[(16 * nt + (lane & 15)) * 64 + ks * 32 + (lane >> 4) * 8];
#pragma unroll
        for (int mt = 0; mt < 2; ++mt) acc[mt][nt] = mfma16(af[mt], bf, acc[mt][nt]);
      }
    }
    __syncthreads();
  }
  const bool obf = (OM == 1) ? (*flag != 0) : true;
#pragma unroll
  for (int mt = 0; mt < 2; ++mt)
#pragma unroll
    for (int nt = 0; nt < 8; ++nt) {
      int rg = m0 + 32 * wv + 16 * mt + ((lane >> 4) << 2);
      int cg = n0 + 16 * nt + (lane & 15);
      float bv = bf2f(bias[cg]);
#pragma unroll
      for (int r = 0; r < 4; ++r) {
        float o = acc[mt][nt][r] + bv;
        if (OM == 2) {
          int row = rg + r;
          int bb = row >> 12, l = row & 4095;
          size_t dst = ((size_t)((bb * 64 + (l >> 6)) * 16 + (cg >> 6))) * 4096 +
                       (size_t)(l & 63) * 64 + (cg & 63);
          ((u16*)Out)[dst] = f2bf(o);
        } else if (obf) {
          ((u16*)Out)[(size_t)(rg + r) * DD + cg] = f2bf(o);
        } else {
          ((float*)Out)[(size_t)(rg + r) * DD + cg] = o;
        }
      }
    }
}

__global__ __launch_bounds__(256) void k_gemm_qkv(const u16* __restrict__ X,
    const u16* __restrict__ Wq, const u16* __restrict__ bq,
    const u16* __restrict__ Wk, const u16* __restrict__ bk,
    const u16* __restrict__ Wv, const u16* __restrict__ bv,
    u16* __restrict__ Qo /*tiled*/, u16* __restrict__ Ko, u16* __restrict__ Vo) {
  int nb = blockIdx.x;  // 0..23
  int mat = nb >> 3, nt = nb & 7;
  if (mat == 0)      gemm128<2>(X, Wq, bq, Qo, blockIdx.y * 128, nt * 128, nullptr);
  else if (mat == 1) gemm128<0>(X, Wk, bk, Ko, blockIdx.y * 128, nt * 128, nullptr);
  else               gemm128<0>(X, Wv, bv, Vo, blockIdx.y * 128, nt * 128, nullptr);
}

__global__ __launch_bounds__(256) void k_gemm_o(const u16* __restrict__ A,
    const u16* __restrict__ Wo, const u16* __restrict__ bo, void* __restrict__ Out,
    const int* __restrict__ flag) {
  gemm128<1>(A, Wo, bo, Out, blockIdx.y * 128, blockIdx.x * 128, flag);
}

// ---------------- prep: per (chunk, batch): beta, T2, U0 (over V), A=tril(QK^T),
//   W = T2@K -> Wt (64x64 tiles), K^T -> KTt (64x64 tiles). Q read from tiled layout. --------------
__global__ __launch_bounds__(256) void k_prep(const u16* __restrict__ Qtl, const u16* __restrict__ K,
                                              u16* __restrict__ V /* V in, U0 out (in place) */,
                                              u16* __restrict__ Aout, u16* __restrict__ Wt,
                                              u16* __restrict__ KTt) {
  const int ch = blockIdx.x, b = blockIdx.y;
  const size_t row0 = (size_t)b * LL + (size_t)ch * CC;
  const int tid = threadIdx.x, lane = tid & 63, wv = tid >> 6;

  __shared__ __attribute__((aligned(16))) float Gs[64 * 65];   // reused as KTs (u16 64x72) in phase B
  __shared__ __attribute__((aligned(16))) float Ts[64 * 65];   // reused as VTs (u16 64x72) in phase B
  __shared__ __attribute__((aligned(16))) u16 Kt[64 * 64];
  __shared__ __attribute__((aligned(16))) u16 Qt[64 * 64];
  __shared__ __attribute__((aligned(16))) u16 T2s[64 * 72];
  __shared__ float betas[64];

  float4_ accG[4], accA[4];
#pragma unroll
  for (int ct = 0; ct < 4; ++ct) { accG[ct] = (float4_)0.f; accA[ct] = (float4_)0.f; }

  // phase A: G = K K^T, Araw = Q K^T  (K-streamed; Q from tiled layout)
  for (int kk = 0; kk < DD; kk += 64) {
    const size_t qtb = ((size_t)(b * NCH + ch) * 16 + (kk >> 6)) * 4096;
#pragma unroll
    for (int i = 0; i < 2; ++i) {
      int e = tid + 256 * i;
      int row = e >> 3, col = (e & 7) * 8;
      *(short8*)&Kt[row * 64 + col] = *(const short8*)(K + (row0 + row) * DD + kk + col);
      *(short8*)&Qt[e * 8] = *(const short8*)(Qtl + qtb + (size_t)e * 8);
    }
    __syncthreads();
#pragma unroll
    for (int ks = 0; ks < 2; ++ks) {
      short8 ak = *(const short8*)&Kt[(16 * wv + (lane & 15)) * 64 + ks * 32 + (lane >> 4) * 8];
      short8 aq = *(const short8*)&Qt[(16 * wv + (lane & 15)) * 64 + ks * 32 + (lane >> 4) * 8];
#pragma unroll
      for (int ct = 0; ct < 4; ++ct) {
        short8 bk = *(const short8*)&Kt[(16 * ct + (lane & 15)) * 64 + ks * 32 + (lane >> 4) * 8];
        accG[ct] = mfma16(ak, bk, accG[ct]);
        accA[ct] = mfma16(aq, bk, accA[ct]);
      }
    }
    __syncthreads();
  }
  u16* Abase = Aout + (size_t)(b * NCH + ch) * (CC * CC);
#pragma unroll
  for (int ct = 0; ct < 4; ++ct) {
    int i0 = 16 * wv + ((lane >> 4) << 2);
    int c = 16 * ct + (lane & 15);
#pragma unroll
    for (int r = 0; r < 4; ++r) {
      int i = i0 + r;
      Gs[i * 65 + c] = accG[ct][r];
      Abase[i * 64 + c] = f2bf((c <= i) ? accA[ct][r] : 0.f);
    }
  }
  __syncthreads();
  if (tid < 64) betas[tid] = 1.f / (Gs[tid * 65 + tid] + 1e-6f);
  __syncthreads();
  for (int e = tid; e < 4096; e += 256) {
    int i = e >> 6, c = e & 63;
    Ts[i * 65 + c] = (c < i) ? (-betas[i] * Gs[i * 65 + c]) : 0.f;
  }
  __syncthreads();
  // forward substitution (reference exact recurrence)
  for (int i = 1; i < 64; ++i) {
    float rv = 0.f, acc = 0.f;
    if (tid < 64) {
      rv = Ts[i * 65 + tid];
      for (int j = 1; j < i; ++j) {
        float a = __shfl(rv, j);
        acc += a * Ts[j * 65 + tid];
      }
    }
    __syncthreads();
    if (tid < i) Ts[i * 65 + tid] = rv + acc;
    __syncthreads();
  }
  if (tid < 64) Ts[tid * 65 + tid] += 1.f;
  __syncthreads();
  for (int e = tid; e < 4096; e += 256) {
    int i = e >> 6, j = e & 63;
    T2s[i * 72 + j] = f2bf(Ts[i * 65 + j] * betas[j]);
  }
  __syncthreads();

  // phase B: U0 = T2@V (over V); W = T2@K -> Wt tiled; K^T tile -> KTt tiled
  u16* KTs = (u16*)Gs;  // 64 x 72
  u16* VTs = (u16*)Ts;  // 64 x 72
  for (int kk = 0; kk < DD; kk += 64) {
    const size_t tlb = ((size_t)(b * NCH + ch) * 16 + (kk >> 6)) * 4096;
#pragma unroll
    for (int rep = 0; rep < 2; ++rep) {
      int t = tid >> 2;
      int c0 = (tid & 3) * 8 + rep * 32;
      short8 vv = *(const short8*)(V + (row0 + t) * DD + kk + c0);
      short8 vk = *(const short8*)(K + (row0 + t) * DD + kk + c0);
#pragma unroll
      for (int e = 0; e < 8; ++e) { VTs[(c0 + e) * 72 + t] = (u16)vv[e]; KTs[(c0 + e) * 72 + t] = (u16)vk[e]; }
    }
    __syncthreads();
    // emit K^T tile (64 dj x 64 t) contiguous
#pragma unroll
    for (int w2 = 0; w2 < 2; ++w2) {
      int e = tid + 256 * w2;
      int jl = e >> 3, toff = (e & 7) * 8;
      *(short8*)(KTt + tlb + (size_t)jl * 64 + toff) = *(const short8*)&KTs[jl * 72 + toff];
    }
    float4_ accU[4], accW[4];
#pragma unroll
    for (int ct = 0; ct < 4; ++ct) { accU[ct] = (float4_)0.f; accW[ct] = (float4_)0.f; }
#pragma unroll
    for (int ks = 0; ks < 2; ++ks) {
      short8 a2 = *(const short8*)&T2s[(16 * wv + (lane & 15)) * 72 + ks * 32 + (lane >> 4) * 8];
#pragma unroll
      for (int ct = 0; ct < 4; ++ct) {
        short8 bu = *(const short8*)&VTs[(16 * ct + (lane & 15)) * 72 + ks * 32 + (lane >> 4) * 8];
        short8 bw = *(const short8*)&KTs[(16 * ct + (lane & 15)) * 72 + ks * 32 + (lane >> 4) * 8];
        accU[ct] = mfma16(a2, bu, accU[ct]);
        accW[ct] = mfma16(a2, bw, accW[ct]);
      }
    }
#pragma unroll
    for (int ct = 0; ct < 4; ++ct) {
      int i0 = 16 * wv + ((lane >> 4) << 2);
      int cl = 16 * ct + (lane & 15);
#pragma unroll
      for (int r = 0; r < 4; ++r) {
        V[(row0 + i0 + r) * DD + kk + cl] = f2bf(accU[ct][r]);        // U0 over V (row-major)
        Wt[tlb + (size_t)(i0 + r) * 64 + cl] = f2bf(accW[ct][r]);     // W tiled
      }
    }
    __syncthreads();
  }
}

// ---------------- fused scan: persistent WG per (b, 32-col slice). S^T[32][1028] f32 in LDS. ----
// W/Q/K^T streamed via async global_load_lds into a 3-slot staging ring (8KB units),
// counted vmcnt(2) + raw s_barrier (in-flight next stage never drained). Tiles XOR-swizzled
// at the source so fragment ds_reads are ~2-way-conflict-free. u/oq in registers (no atomics);
// u crosses waves once per chunk through uT.
__global__ __launch_bounds__(256, 1) void k_scan_fused(
    const u16* __restrict__ Qt, const u16* __restrict__ Wt, const u16* __restrict__ KTt,
    u16* __restrict__ U0 /* U0 in, o out in place */, const u16* __restrict__ Ag) {
  __shared__ __attribute__((aligned(16))) float S[32 * 1028];   // 131584 B
  __shared__ __attribute__((aligned(16))) u16 stg[3 * 4096];    //  24576 B (3 x 8KB slots)
  __shared__ __attribute__((aligned(16))) u16 uT[32 * 72];      //   4608 B  -> 160768 total

  const int b = blockIdx.x & 7;               // XCD-affinity: batch b -> XCD b
  const int dc0 = (blockIdx.x >> 3) * 32;     // 32-col slice
  const int tid = threadIdx.x, lane = tid & 63, wv = tid >> 6;
  const int r15 = lane & 15, hi = lane >> 4;
  const int arow = 16 * wv + r15;                                   // A-frag row (t or dj local)
  const int aoff = arow * 32 + ((hi ^ ((arow >> 1) & 3)) << 3);     // ph1 half-tile read (swz)
  const int koff0 = arow * 64 + ((hi ^ (arow & 7)) << 3);           // ph3 kf0 (swz)
  const int koff1 = arow * 64 + (((4 + hi) ^ (arow & 7)) << 3);     // ph3 kf1 (swz)
  const int tC = 16 * wv + hi * 4;                                  // C-frag t base
  // staging source offsets (pre-swizzled so LDS dest is linear: dest u16 = tid*8 [+2048])
  const int s_row = tid >> 2;
  const int s_src = s_row * 64 + (((tid & 3) ^ ((s_row >> 1) & 3)) << 3);      // ph1 half-tiles
  const int l1 = tid + 256;
  const int k_src0 = (tid >> 3) * 64 + (((tid & 7) ^ ((tid >> 3) & 7)) << 3);  // ph3 full tile lo
  const int k_src1 = (l1 >> 3) * 64 + (((l1 & 7) ^ ((l1 >> 3) & 7)) << 3);     // ph3 full tile hi
  u16* wdst = &stg[wv * 512];   // wave-uniform dest base; +slot*4096 (+2048 for 2nd half)

  for (int i = tid; i < 32 * 1028; i += 256) S[i] = 0.f;
  __syncthreads();

  for (int ch = 0; ch < NCH; ++ch) {
    const size_t row0 = (size_t)b * LL + (size_t)ch * CC;
    const size_t tb = (size_t)(b * NCH + ch) * 16;

    // early: U0 fragment loads (consumed at uT write)
    u16 u0r[2][4];
#pragma unroll
    for (int dt = 0; dt < 2; ++dt)
#pragma unroll
      for (int r = 0; r < 4; ++r)
        u0r[dt][r] = U0[(row0 + tC + r) * DD + dc0 + dt * 16 + r15];

    float4_ uacc[2], oqa[2];
    uacc[0] = (float4_)0.f; uacc[1] = (float4_)0.f;
    oqa[0] = (float4_)0.f;  oqa[1] = (float4_)0.f;

    auto issue1 = [&](int hs) {
      const int s = hs >> 1, ks = (hs & 1) * 32, slot = hs % 3;
      gld_lds16(Wt + (tb + s) * 4096 + ks + s_src, wdst + slot * 4096);
      gld_lds16(Qt + (tb + s) * 4096 + ks + s_src, wdst + slot * 4096 + 2048);
    };
    issue1(0); issue1(1);

    // ---- phase 1: u -= W@S, oq += Q@S over 32 half-tiles (k=32 each)
#pragma unroll 1
    for (int hs = 0; hs < 31; ++hs) {
      asm volatile("s_waitcnt vmcnt(2)" ::: "memory");
      __builtin_amdgcn_s_barrier();
      __builtin_amdgcn_sched_barrier(0);
      if (hs + 2 < 32) issue1(hs + 2);
      const int slot = hs % 3;
      const u16* wb = &stg[slot * 4096];
      short8 afw = *(const short8*)&wb[aoff];
      short8 afq = *(const short8*)&wb[2048 + aoff];
      const int jb = hs * 32 + hi * 8;
#pragma unroll
      for (int dt = 0; dt < 2; ++dt) {
        const float* sp = &S[(dt * 16 + r15) * 1028 + jb];
        float4_ x0 = *(const float4_*)sp;
        float4_ x1 = *(const float4_*)(sp + 4);
        S8U u;
        u.w[0] = cvtpk(x0[0], x0[1]); u.w[1] = cvtpk(x0[2], x0[3]);
        u.w[2] = cvtpk(x1[0], x1[1]); u.w[3] = cvtpk(x1[2], x1[3]);
        uacc[dt] = mfma16(afw, u.s, uacc[dt]);
        oqa[dt]  = mfma16(afq, u.s, oqa[dt]);
      }
    }
    {  // tail hs=31
      asm volatile("s_waitcnt vmcnt(0)" ::: "memory");
      __builtin_amdgcn_s_barrier();
      __builtin_amdgcn_sched_barrier(0);
      const int slot = 31 % 3;
      const u16* wb = &stg[slot * 4096];
      short8 afw = *(const short8*)&wb[aoff];
      short8 afq = *(const short8*)&wb[2048 + aoff];
      const int jb = 31 * 32 + hi * 8;
#pragma unroll
      for (int dt = 0; dt < 2; ++dt) {
        const float* sp = &S[(dt * 16 + r15) * 1028 + jb];
        float4_ x0 = *(const float4_*)sp;
        float4_ x1 = *(const float4_*)(sp + 4);
        S8U u;
        u.w[0] = cvtpk(x0[0], x0[1]); u.w[1] = cvtpk(x0[2], x0[3]);
        u.w[2] = cvtpk(x1[0], x1[1]); u.w[3] = cvtpk(x1[2], x1[3]);
        uacc[dt] = mfma16(afw, u.s, uacc[dt]);
        oqa[dt]  = mfma16(afq, u.s, oqa[dt]);
      }
    }
    // u = U0 - acc -> uT (bf16, [dc][t])
#pragma unroll
    for (int dt = 0; dt < 2; ++dt) {
      float v0 = bf2f(u0r[dt][0]) - uacc[dt][0];
      float v1 = bf2f(u0r[dt][1]) - uacc[dt][1];
      float v2 = bf2f(u0r[dt][2]) - uacc[dt][2];
      float v3 = bf2f(u0r[dt][3]) - uacc[dt][3];
      uint32_t* d = (uint32_t*)&uT[(dt * 16 + r15) * 72 + tC];
      d[0] = cvtpk(v0, v1);
      d[1] = cvtpk(v2, v3);
    }
    __syncthreads();   // barrier A: uT complete

    short8 ub[2][2];
#pragma unroll
    for (int dt = 0; dt < 2; ++dt)
#pragma unroll
      for (int ks = 0; ks < 2; ++ks)
        ub[dt][ks] = *(const short8*)&uT[(dt * 16 + r15) * 72 + ks * 32 + hi * 8];
    const u16* Ab = Ag + (size_t)(b * NCH + ch) * (CC * CC);
    short8 afA0 = *(const short8*)(Ab + arow * 64 + hi * 8);
    short8 afA1 = *(const short8*)(Ab + arow * 64 + 32 + hi * 8);

    auto issue3 = [&](int ts) {
      const int slot = ts % 3;
      gld_lds16(KTt + (tb + ts) * 4096 + k_src0, wdst + slot * 4096);
      gld_lds16(KTt + (tb + ts) * 4096 + k_src1, wdst + slot * 4096 + 2048);
    };
    issue3(0); issue3(1);

    // ---- phase 3: S += K^T@u over 16 full tiles
#pragma unroll 1
    for (int ts = 0; ts < 15; ++ts) {
      asm volatile("s_waitcnt vmcnt(2)" ::: "memory");
      __builtin_amdgcn_s_barrier();
      __builtin_amdgcn_sched_barrier(0);
      if (ts + 2 < 16) issue3(ts + 2);
      const int slot = ts % 3;
      const u16* kb = &stg[slot * 4096];
      short8 kf0 = *(const short8*)&kb[koff0];
      short8 kf1 = *(const short8*)&kb[koff1];
#pragma unroll
      for (int dt = 0; dt < 2; ++dt) {
        float* sp = &S[(dt * 16 + r15) * 1028 + ts * 64 + wv * 16 + hi * 4];
        float4_ c = *(const float4_*)sp;
        c = mfma16(kf0, ub[dt][0], c);
        c = mfma16(kf1, ub[dt][1], c);
        *(float4_*)sp = c;
      }
    }
    {  // tail ts=15
      asm volatile("s_waitcnt vmcnt(0)" ::: "memory");
      __builtin_amdgcn_s_barrier();
      __builtin_amdgcn_sched_barrier(0);
      const u16* kb = &stg[(15 % 3) * 4096];
      short8 kf0 = *(const short8*)&kb[koff0];
      short8 kf1 = *(const short8*)&kb[koff1];
#pragma unroll
      for (int dt = 0; dt < 2; ++dt) {
        float* sp = &S[(dt * 16 + r15) * 1028 + 15 * 64 + wv * 16 + hi * 4];
        float4_ c = *(const float4_*)sp;
        c = mfma16(kf0, ub[dt][0], c);
        c = mfma16(kf1, ub[dt][1], c);
        *(float4_*)sp = c;
      }
    }
    // ---- phase 4: o = A@u + oq -> over U0 rows (in place; same wave read U0 earlier)
#pragma unroll
    for (int dt = 0; dt < 2; ++dt) {
      float4_ c;
#pragma unroll
      for (int r = 0; r < 4; ++r) c[r] = oqa[dt][r];
      c = mfma16(afA0, ub[dt][0], c);
      c = mfma16(afA1, ub[dt][1], c);
#pragma unroll
      for (int r = 0; r < 4; ++r)
        U0[(row0 + tC + r) * DD + dc0 + dt * 16 + r15] = f2bf(c[r]);
    }
    __syncthreads();   // end of chunk: S/uT/stg consistent, vmcnt drained
  }
}

extern "C" void kernel_launch(void* const* d_in, const int* in_sizes, int n_in,
                              void* d_out, int out_size, void* d_ws, size_t ws_size,
                              hipStream_t stream) {
  (void)in_sizes; (void)n_in; (void)out_size; (void)ws_size;
  const void* X  = d_in[0];
  // d_in[1] = chunk (=64), hard-coded
  const void* Wq = d_in[2]; const void* bq = d_in[3];
  const void* Wk = d_in[4]; const void* bk = d_in[5];
  const void* Wv = d_in[6]; const void* bv = d_in[7];
  const void* Wo = d_in[8]; const void* bo = d_in[9];

  char* ws = (char*)d_ws;
  int* flag = (int*)ws;
  char* p = ws + 256;
  const size_t E2 = (size_t)NB * LL * DD * 2;                  // 64 MiB
  u16* xb   = (u16*)p; p += E2;                                // X bf16; KTt tiled overlays after QKV
  u16* ktt  = xb;
  u16* wqb  = (u16*)p; p += (size_t)DD * DD * 2;
  u16* wkb  = (u16*)p; p += (size_t)DD * DD * 2;
  u16* wvb  = (u16*)p; p += (size_t)DD * DD * 2;
  u16* wob  = (u16*)p; p += (size_t)DD * DD * 2;
  u16* bqb  = (u16*)p; p += 4096;
  u16* bkb  = (u16*)p; p += 4096;
  u16* bvb  = (u16*)p; p += 4096;
  u16* bob  = (u16*)p; p += 4096;
  u16* q_tl = (u16*)p; p += E2;                                // Q tiled (64x64 tiles)
  u16* k_ws = (u16*)p; p += E2;                                // K row-major (dead after prep)
  u16* v_ws = (u16*)p; p += E2;                                // V -> U0 -> o in place
  u16* a_ws = (u16*)p; p += (size_t)NB * NCH * CC * CC * 2;    // 4 MiB
  u16* w_tl = (u16*)p; p += E2;                                // W tiled
  // total ~332 MiB

  k_detect<<<1, 64, 0, stream>>>((const uint32_t*)X, flag);
  const long nX = (long)NB * LL * DD / 8;
  k_convert<<<(nX + 255) / 256, 256, 0, stream>>>(X, xb, nX, flag);
  const long nW = (long)DD * DD / 8;
  k_convert<<<(nW + 255) / 256, 256, 0, stream>>>(Wq, wqb, nW, flag);
  k_convert<<<(nW + 255) / 256, 256, 0, stream>>>(Wk, wkb, nW, flag);
  k_convert<<<(nW + 255) / 256, 256, 0, stream>>>(Wv, wvb, nW, flag);
  k_convert<<<(nW + 255) / 256, 256, 0, stream>>>(Wo, wob, nW, flag);
  const long nBias = DD / 8;
  k_convert<<<1, 256, 0, stream>>>(bq, bqb, nBias, flag);
  k_convert<<<1, 256, 0, stream>>>(bk, bkb, nBias, flag);
  k_convert<<<1, 256, 0, stream>>>(bv, bvb, nBias, flag);
  k_convert<<<1, 256, 0, stream>>>(bo, bob, nBias, flag);

  k_gemm_qkv<<<dim3(24, 256), 256, 0, stream>>>(xb, wqb, bqb, wkb, bkb, wvb, bvb, q_tl, k_ws, v_ws);
  k_prep<<<dim3(64, 8), 256, 0, stream>>>(q_tl, k_ws, v_ws, a_ws, w_tl, ktt);
  k_scan_fused<<<dim3(256), 256, 0, stream>>>(q_tl, w_tl, ktt, v_ws, a_ws);
  k_gemm_o<<<dim3(8, 256), 256, 0, stream>>>(v_ws, wob, bob, d_out, flag);
}